// Round 8
// baseline (1276.847 us; speedup 1.0000x reference)
//
#include <hip/hip_runtime.h>
#include <cstdint>
#include <cstddef>

// ---------------------------------------------------------------------------
// TransformerMultiViewFusion (MI355X / gfx950), round 8.
//
//  R8 change: ffn_fused_k v4 — two-hop weight staging. R7's ping-pong with
//  global_load_lds gained only 8%: __syncthreads drains vmcnt(0) while any
//  global_load_lds is outstanding, so every barrier killed the prefetch
//  (~78cyc cover vs ~200cyc L2 latency). v4 stages weights as
//  global_load_dwordx4 -> VGPR (rp[2][4], waited fine-grained at the
//  ds_write_b128 use, NOT at barriers) -> LDS. Pipeline: ld(s+2) -> 16-MFMA
//  consume(s) -> ds_write(s+1) -> barrier(lgkm-only). ~2 steps of latency
//  cover per load. Barriers 9->8/hc (Ts write folded into last phase-A step).
//
//  Workspace: X@0 | QKV@37748736 | SA@150994944 | Xf@188743680 |
//             WpB@198180864 | Wb@226492416
// ---------------------------------------------------------------------------

typedef __bf16 bf16;
typedef __bf16 bf16x8 __attribute__((ext_vector_type(8)));
typedef __bf16 bf16x4 __attribute__((ext_vector_type(4)));
typedef float  f32x4  __attribute__((ext_vector_type(4)));

__device__ __forceinline__ void async_copy16(const void* g, void* l)
{
    __builtin_amdgcn_global_load_lds(
        (__attribute__((address_space(1))) void*)g,
        (__attribute__((address_space(3))) void*)l,
        16, 0, 0);
}

// --------------------------------------------------------------------------
// all 5 weight packs in one launch. 1589248 = 6208*256 exactly.
// --------------------------------------------------------------------------
__global__ void pack_all_k(const float* __restrict__ s0, const float* __restrict__ s1,
                           const float* __restrict__ s2, const float* __restrict__ s3,
                           const float* __restrict__ s4,
                           bf16* __restrict__ d0, bf16* __restrict__ d1,
                           bf16* __restrict__ d2, bf16* __restrict__ d3,
                           bf16* __restrict__ d4)
{
    const int i = blockIdx.x * 256 + threadIdx.x;
    if (i < 393216)       d0[i] = (bf16)s0[i];
    else if (i < 524288)  d1[i - 393216] = (bf16)s1[i - 393216];
    else if (i < 1048576) d2[i - 524288] = (bf16)s2[i - 524288];
    else if (i < 1572864) d3[i - 1048576] = (bf16)s3[i - 1048576];
    else                  d4[i - 1572864] = (bf16)s4[i - 1572864];
}

// --------------------------------------------------------------------------
// feat transpose-pack: Xf[t][c] = (bf16)feat[cam][b][c][hw]
// --------------------------------------------------------------------------
__global__ __launch_bounds__(256) void feat_pack_k(const float* __restrict__ feat,
                                                   bf16* __restrict__ Xf)
{
    __shared__ float ft[64][68];

    const int tid  = threadIdx.x;
    const int camb = blockIdx.y;
    const int cam  = camb >> 1;
    const int b    = camb & 1;
    const int hw0  = blockIdx.x * 64;

    const float* fb = feat + (size_t)camb * 64 * 9216 + hw0;
#pragma unroll
    for (int rep = 0; rep < 16; ++rep) {
        const int idx = rep * 256 + tid;
        const int c = idx >> 6, p = idx & 63;
        ft[p][c] = fb[(size_t)c * 9216 + p];
    }
    __syncthreads();

    const int pbase = b * 9216 + hw0;
#pragma unroll
    for (int rep = 0; rep < 2; ++rep) {
        const int idx = rep * 256 + tid;
        const int p = idx >> 3, cc = idx & 7;
        const f32x4 a = *(const f32x4*)(&ft[p][cc * 8]);
        const f32x4 c4 = *(const f32x4*)(&ft[p][cc * 8 + 4]);
        bf16x8 v;
#pragma unroll
        for (int i = 0; i < 4; ++i) { v[i] = (bf16)a[i]; v[4 + i] = (bf16)c4[i]; }
        const size_t t = (size_t)(pbase + p) * 4 + cam;
        *(bf16x8*)(Xf + t * 64 + cc * 8) = v;
    }
}

// --------------------------------------------------------------------------
// GEMM-BT: C[M,N] = A[M,K] @ B[N,K]^T + bias[N], bf16 in/out. 128x128 tile.
// --------------------------------------------------------------------------
template <bool RELU>
__global__ __launch_bounds__(256, 2) void gemm_bt(
    const bf16* __restrict__ A, const bf16* __restrict__ B,
    const float* __restrict__ bias, bf16* __restrict__ C,
    int N, int K)
{
    __shared__ __align__(16) bf16 As[128 * 64];
    __shared__ __align__(16) bf16 Bs[128 * 64];

    const int tid  = threadIdx.x;
    const int lane = tid & 63;
    const int wv   = tid >> 6;
    const int wm   = wv >> 1;
    const int wn   = wv & 1;
    const int bm   = blockIdx.y * 128;
    const int bn   = blockIdx.x * 128;

    const int r8  = lane >> 3;
    const int p8  = lane & 7;
    const int gch = p8 ^ r8;

    const int quad = lane >> 4;
    const int l16  = lane & 15;

    f32x4 acc[4][4] = {};

    for (int k0 = 0; k0 < K; k0 += 64) {
#pragma unroll
        for (int inst = 0; inst < 4; ++inst) {
            const int row = wv * 32 + inst * 8 + r8;
            const bf16* ga = A + (size_t)(bm + row) * K + (k0 + gch * 8);
            const bf16* gb = B + (size_t)(bn + row) * K + (k0 + gch * 8);
            async_copy16(ga, (char*)As + (wv * 4 + inst) * 1024);
            async_copy16(gb, (char*)Bs + (wv * 4 + inst) * 1024);
        }
        __syncthreads();

#pragma unroll
        for (int kk = 0; kk < 2; ++kk) {
            bf16x8 af[4], bfr[4];
            const int lch = kk * 4 + quad;
#pragma unroll
            for (int i = 0; i < 4; ++i) {
                const int m = wm * 64 + i * 16 + l16;
                af[i] = *(const bf16x8*)((const char*)As + (m * 8 + (lch ^ (m & 7))) * 16);
                const int n = wn * 64 + i * 16 + l16;
                bfr[i] = *(const bf16x8*)((const char*)Bs + (n * 8 + (lch ^ (n & 7))) * 16);
            }
#pragma unroll
            for (int i = 0; i < 4; ++i)
#pragma unroll
                for (int j = 0; j < 4; ++j)
                    acc[i][j] = __builtin_amdgcn_mfma_f32_16x16x32_bf16(
                        af[i], bfr[j], acc[i][j], 0, 0, 0);
        }
        __syncthreads();
    }

#pragma unroll
    for (int j = 0; j < 4; ++j) {
        const int n = bn + wn * 64 + j * 16 + l16;
        const float bv = bias[n];
#pragma unroll
        for (int i = 0; i < 4; ++i) {
            const int mb = bm + wm * 64 + i * 16 + quad * 4;
#pragma unroll
            for (int r = 0; r < 4; ++r) {
                float v = acc[i][j][r] + bv;
                if (RELU) v = fmaxf(v, 0.f);
                C[(size_t)(mb + r) * N + n] = (bf16)v;
            }
        }
    }
}

// --------------------------------------------------------------------------
// GEMM-BT + bias + residual + LayerNorm (Wo path, K=256). 128x256 tile.
// --------------------------------------------------------------------------
__global__ __launch_bounds__(256, 2) void gemm_ln_k(
    const bf16* __restrict__ A, const bf16* __restrict__ B,
    const float* __restrict__ bias, const bf16* __restrict__ Xres,
    const float* __restrict__ gam, const float* __restrict__ bet,
    bf16* __restrict__ Xout, int K)
{
    __shared__ __align__(16) bf16 S[24576];
    __shared__ float2 red[128][2];

    const int tid  = threadIdx.x;
    const int lane = tid & 63;
    const int wv   = tid >> 6;
    const int wm   = wv >> 1;
    const int wn   = wv & 1;
    const int bm   = blockIdx.x * 128;
    const int quad = lane >> 4;
    const int l16  = lane & 15;

    f32x4 acc[4][8] = {};

    for (int k0 = 0; k0 < K; k0 += 64) {
#pragma unroll
        for (int s = 0; s < 12; ++s) {
            const int L   = s * 256 + tid;
            const int row = L >> 3;
            const int gch = (L & 7) ^ (row & 7);
            const bf16* g = (row < 128)
                ? A + (size_t)(bm + row) * K + (k0 + gch * 8)
                : B + (size_t)(row - 128) * K + (k0 + gch * 8);
            async_copy16(g, (char*)S + (size_t)L * 16);
        }
        __syncthreads();

#pragma unroll
        for (int kk = 0; kk < 2; ++kk) {
            const int lch = kk * 4 + quad;
            bf16x8 af[4], bfr[8];
#pragma unroll
            for (int i = 0; i < 4; ++i) {
                const int m = wm * 64 + i * 16 + l16;
                af[i] = *(const bf16x8*)((const char*)S + (m * 8 + (lch ^ (m & 7))) * 16);
            }
#pragma unroll
            for (int j = 0; j < 8; ++j) {
                const int n = wn * 128 + j * 16 + l16;
                bfr[j] = *(const bf16x8*)((const char*)S + ((128 + n) * 8 + (lch ^ (n & 7))) * 16);
            }
#pragma unroll
            for (int i = 0; i < 4; ++i)
#pragma unroll
                for (int j = 0; j < 8; ++j)
                    acc[i][j] = __builtin_amdgcn_mfma_f32_16x16x32_bf16(
                        af[i], bfr[j], acc[i][j], 0, 0, 0);
        }
        __syncthreads();
    }

    float bv[8], gv[8], bev[8];
#pragma unroll
    for (int j = 0; j < 8; ++j) {
        const int n = wn * 128 + j * 16 + l16;
        bv[j] = bias[n]; gv[j] = gam[n]; bev[j] = bet[n];
    }

#pragma unroll
    for (int i = 0; i < 4; ++i) {
#pragma unroll
        for (int r = 0; r < 4; ++r) {
            const int rl  = wm * 64 + i * 16 + quad * 4 + r;
            const size_t row = (size_t)(bm + rl);
            float s1 = 0.f, s2 = 0.f;
#pragma unroll
            for (int j = 0; j < 8; ++j) {
                const int n = wn * 128 + j * 16 + l16;
                const float v = acc[i][j][r] + bv[j] + (float)Xres[row * 256 + n];
                acc[i][j][r] = v;
                s1 += v; s2 += v * v;
            }
#pragma unroll
            for (int off = 1; off < 16; off <<= 1) {
                s1 += __shfl_xor(s1, off, 64);
                s2 += __shfl_xor(s2, off, 64);
            }
            if (l16 == 0) red[rl][wn] = make_float2(s1, s2);
        }
    }
    __syncthreads();

#pragma unroll
    for (int i = 0; i < 4; ++i) {
#pragma unroll
        for (int r = 0; r < 4; ++r) {
            const int rl = wm * 64 + i * 16 + quad * 4 + r;
            const float2 p0 = red[rl][0], p1 = red[rl][1];
            const float mu  = (p0.x + p1.x) * (1.f / 256.f);
            const float ex2 = (p0.y + p1.y) * (1.f / 256.f);
            const float rstd = rsqrtf(fmaxf(ex2 - mu * mu, 0.f) + 1e-5f);
            const size_t row = (size_t)(bm + rl);
#pragma unroll
            for (int j = 0; j < 8; ++j) {
                const int n = wn * 128 + j * 16 + l16;
                Xout[row * 256 + n] = (bf16)((acc[i][j][r] - mu) * rstd * gv[j] + bev[j]);
            }
        }
    }
}

// --------------------------------------------------------------------------
// ffn weight-step s (0..63): hc = s>>3; q = s&7.
//  q<4 : W1 quarter [128 h][64 k], slot = c ^ (row&7)
//  q>=4: W2 quarter [256 n][32 k], paired rows: LDS row = n>>1,
//        slot = ((n&1)*4 + c) ^ ((n>>1)&7)
// Two-hop: ffn_ld -> VGPR (uint4 x4), ffn_st -> ds_write_b128.
// --------------------------------------------------------------------------
__device__ __forceinline__ void ffn_ld(int s, const bf16* __restrict__ W1,
                                       const bf16* __restrict__ W2,
                                       int tid, uint4* r)
{
    const int hc = s >> 3;
    const int q  = s & 7;
    if (q < 4) {
#pragma unroll
        for (int it = 0; it < 4; ++it) {
            const int L = it * 256 + tid;
            const int row = L >> 3;
            const int c = (L & 7) ^ (row & 7);
            r[it] = *(const uint4*)(W1 + (size_t)(hc * 128 + row) * 256 + q * 64 + c * 8);
        }
    } else {
#pragma unroll
        for (int it = 0; it < 4; ++it) {
            const int L = it * 256 + tid;
            const int r128 = L >> 3;
            const int g = (L & 7) ^ (r128 & 7);
            const int n = r128 * 2 + (g >> 2);
            const int c = g & 3;
            r[it] = *(const uint4*)(W2 + (size_t)n * 1024 + hc * 128 + (q - 4) * 32 + c * 8);
        }
    }
}

__device__ __forceinline__ void ffn_st(int s, char* stg, int tid, const uint4* r)
{
    char* buf = stg + (size_t)(s & 1) * 16384;
#pragma unroll
    for (int it = 0; it < 4; ++it)
        *(uint4*)(buf + (size_t)(it * 256 + tid) * 16) = r[it];
}

// --------------------------------------------------------------------------
// Fused FFN v4: Xout = LN(X + relu(X@W1^T+b1)@W2^T + b2)*gam + bet, in-place.
// 64-row tile, grid 1152, 4 waves 2x2. 8 hidden chunks of 128.
// Two-hop staged weights (regs->LDS): barriers are lgkm-only; global load
// latency covered by ~2 steps of pipeline (ld(s+2) issued before consume(s),
// ds_write(s+1) waits AFTER the MFMA cover).
// LDS: Xs 32K | Ts 16K (red aliases) | stage 2x16K = 80KB -> 2 blocks/CU.
// --------------------------------------------------------------------------
__global__ __launch_bounds__(256, 2) void ffn_fused_k(
    const bf16* __restrict__ X,
    const bf16* __restrict__ W1, const float* __restrict__ b1,
    const bf16* __restrict__ W2, const float* __restrict__ b2,
    const float* __restrict__ gam, const float* __restrict__ bet,
    bf16* __restrict__ Xout)
{
    __shared__ __align__(16) char smem[81920];
    bf16* Xs = (bf16*)smem;                       // 64 x 256 (32 slots/row)
    bf16* Ts = (bf16*)(smem + 32768);             // 64 x 128 (16 slots/row)
    float2 (*red)[2] = (float2 (*)[2])(void*)(smem + 32768);   // aliases Ts
    char* stg = smem + 49152;                     // 2 x 16KB

    const int tid  = threadIdx.x;
    const int lane = tid & 63;
    const int wv   = tid >> 6;
    const int wm   = wv >> 1;
    const int wn   = wv & 1;
    const int quad = lane >> 4;
    const int l16  = lane & 15;
    const int bm   = blockIdx.x * 64;

    uint4 rp[2][4];

    // prologue: stage Xs (async LDS), weight step 0 via regs, prefetch step 1
    ffn_ld(0, W1, W2, tid, rp[0]);
#pragma unroll
    for (int it = 0; it < 8; ++it) {
        const int L = it * 256 + tid;
        const int row = L >> 5, slot = L & 31;
        const int gch = (slot & 24) | ((slot ^ row) & 7);
        async_copy16(X + (size_t)(bm + row) * 256 + gch * 8,
                     (char*)Xs + (size_t)L * 16);
    }
    ffn_st(0, stg, tid, rp[0]);
    ffn_ld(1, W1, W2, tid, rp[1]);
    __syncthreads();   // drains Xs async copies (once) + step-0 ds_writes

    f32x4 acc2[2][8] = {};

#pragma unroll 1
    for (int hc = 0; hc < 8; ++hc) {
        f32x4 accA[2][4] = {};

        // ---- phase A: accA = Xs @ W1c^T, 4 steps of 64k
#pragma unroll
        for (int q = 0; q < 4; ++q) {
            const int s = hc * 8 + q;
            ffn_ld(s + 2, W1, W2, tid, rp[s & 1]);
            const char* cur = stg + (size_t)(s & 1) * 16384;
#pragma unroll
            for (int kk = 0; kk < 2; ++kk) {
                const int ch = kk * 4 + quad;          // buffer chunk 0..7
                const int gc = q * 8 + ch;             // Xs chunk 0..31
                bf16x8 af[2], bfr[4];
#pragma unroll
                for (int i = 0; i < 2; ++i) {
                    const int m  = wm * 32 + i * 16 + l16;
                    const int sl = (gc & 24) | ((gc ^ m) & 7);
                    af[i] = *(const bf16x8*)((const char*)Xs + (m * 32 + sl) * 16);
                }
#pragma unroll
                for (int j = 0; j < 4; ++j) {
                    const int n  = wn * 64 + j * 16 + l16;
                    const int sl = ch ^ (n & 7);
                    bfr[j] = *(const bf16x8*)(cur + (n * 8 + sl) * 16);
                }
#pragma unroll
                for (int i = 0; i < 2; ++i)
#pragma unroll
                    for (int j = 0; j < 4; ++j)
                        accA[i][j] = __builtin_amdgcn_mfma_f32_16x16x32_bf16(
                            af[i], bfr[j], accA[i][j], 0, 0, 0);
            }
            ffn_st(s + 1, stg, tid, rp[(s + 1) & 1]);
            if (q == 3) {
                // Ts = relu(accA + b1)  (Ts readers finished in prev hc)
#pragma unroll
                for (int j = 0; j < 4; ++j) {
                    const int h  = wn * 64 + j * 16 + l16;
                    const float bb = b1[hc * 128 + h];
                    const int g  = h >> 3;
#pragma unroll
                    for (int i = 0; i < 2; ++i)
#pragma unroll
                        for (int r = 0; r < 4; ++r) {
                            const int m  = wm * 32 + i * 16 + quad * 4 + r;
                            const int sl = (g & 8) | ((g ^ m) & 7);
                            const float v = fmaxf(accA[i][j][r] + bb, 0.f);
                            *((bf16*)((char*)Ts + (m * 16 + sl) * 16 + (h & 7) * 2)) = (bf16)v;
                        }
                }
            }
            __syncthreads();
        }

        // ---- phase B: acc2 += Ts @ W2c^T, 4 steps of 32k
#pragma unroll
        for (int q = 0; q < 4; ++q) {
            const int s = hc * 8 + 4 + q;
            if (s + 2 < 64) ffn_ld(s + 2, W1, W2, tid, rp[s & 1]);
            const char* cur = stg + (size_t)(s & 1) * 16384;
            const int tc = q * 4 + quad;               // Ts chunk 0..15
            bf16x8 af[2], bfr[8];
#pragma unroll
            for (int i = 0; i < 2; ++i) {
                const int m  = wm * 32 + i * 16 + l16;
                const int sl = (tc & 8) | ((tc ^ m) & 7);
                af[i] = *(const bf16x8*)((const char*)Ts + (m * 16 + sl) * 16);
            }
#pragma unroll
            for (int j = 0; j < 8; ++j) {
                const int n  = wn * 128 + j * 16 + l16;
                const int sl = (((n & 1) * 4 + quad) ^ ((n >> 1) & 7)) & 7;
                bfr[j] = *(const bf16x8*)(cur + ((n >> 1) * 8 + sl) * 16);
            }
#pragma unroll
            for (int i = 0; i < 2; ++i)
#pragma unroll
                for (int j = 0; j < 8; ++j)
                    acc2[i][j] = __builtin_amdgcn_mfma_f32_16x16x32_bf16(
                        af[i], bfr[j], acc2[i][j], 0, 0, 0);
            if (s + 1 < 64) ffn_st(s + 1, stg, tid, rp[(s + 1) & 1]);
            __syncthreads();
        }
    }

    // ---- epilogue: bias + residual (from Xs) + LayerNorm
    float bv[8], gv[8], bev[8];
#pragma unroll
    for (int j = 0; j < 8; ++j) {
        const int n = wn * 128 + j * 16 + l16;
        bv[j] = b2[n]; gv[j] = gam[n]; bev[j] = bet[n];
    }

#pragma unroll
    for (int i = 0; i < 2; ++i) {
#pragma unroll
        for (int r = 0; r < 4; ++r) {
            const int rl = wm * 32 + i * 16 + quad * 4 + r;
            float s1 = 0.f, s2 = 0.f;
#pragma unroll
            for (int j = 0; j < 8; ++j) {
                const int n  = wn * 128 + j * 16 + l16;
                const int gc = n >> 3;
                const int sl = (gc & 24) | ((gc ^ rl) & 7);
                const float xr = (float)*((const bf16*)((const char*)Xs +
                                   (rl * 32 + sl) * 16 + (n & 7) * 2));
                const float v = acc2[i][j][r] + bv[j] + xr;
                acc2[i][j][r] = v;
                s1 += v; s2 += v * v;
            }
#pragma unroll
            for (int off = 1; off < 16; off <<= 1) {
                s1 += __shfl_xor(s1, off, 64);
                s2 += __shfl_xor(s2, off, 64);
            }
            if (l16 == 0) red[rl][wn] = make_float2(s1, s2);
        }
    }
    __syncthreads();

#pragma unroll
    for (int i = 0; i < 2; ++i) {
#pragma unroll
        for (int r = 0; r < 4; ++r) {
            const int rl = wm * 32 + i * 16 + quad * 4 + r;
            const float2 p0 = red[rl][0], p1 = red[rl][1];
            const float mu  = (p0.x + p1.x) * (1.f / 256.f);
            const float ex2 = (p0.y + p1.y) * (1.f / 256.f);
            const float rstd = rsqrtf(fmaxf(ex2 - mu * mu, 0.f) + 1e-5f);
            const size_t row = (size_t)(bm + rl);
#pragma unroll
            for (int j = 0; j < 8; ++j) {
                const int n = wn * 128 + j * 16 + l16;
                Xout[row * 256 + n] = (bf16)((acc2[i][j][r] - mu) * rstd * gv[j] + bev[j]);
            }
        }
    }
}

// --------------------------------------------------------------------------
// attention v2: per sequence (4 tokens), 8 heads x dh=32, softmax over 4.
// --------------------------------------------------------------------------
__global__ __launch_bounds__(256) void attention_k(const bf16* __restrict__ QKV,
                                                   bf16* __restrict__ SA)
{
    __shared__ float qf[4][4][768];
    __shared__ float sc[4][8][4][4];

    const int tid  = threadIdx.x;
    const int wv   = tid >> 6;
    const int lane = tid & 63;
    const int s    = blockIdx.x * 4 + wv;

    const bf16* base = QKV + (size_t)s * 4 * 768;
#pragma unroll
    for (int it = 0; it < 6; ++it) {
        const int idx = it * 64 + lane;
        const bf16x8 v = *(const bf16x8*)(base + idx * 8);
        const int tok = idx / 96;
        const int e   = (idx % 96) * 8;
        f32x4 f0, f1;
#pragma unroll
        for (int i = 0; i < 4; ++i) { f0[i] = (float)v[i]; f1[i] = (float)v[4 + i]; }
        *(f32x4*)(&qf[wv][tok][e])     = f0;
        *(f32x4*)(&qf[wv][tok][e + 4]) = f1;
    }
    __syncthreads();

#pragma unroll
    for (int rep = 0; rep < 2; ++rep) {
        const int t = rep * 64 + lane;
        const int h = t >> 4, i = (t >> 2) & 3, j = t & 3;
        const float* q = &qf[wv][i][h * 32];
        const float* k = &qf[wv][j][256 + h * 32];
        float a = 0.f;
#pragma unroll
        for (int dd = 0; dd < 32; ++dd) {
            const int d = (dd + lane) & 31;
            a += q[d] * k[d];
        }
        sc[wv][h][i][j] = a * 0.17677669529663687f;
    }
    __syncthreads();

    if (lane < 32) {
        const int h = lane >> 2, i = lane & 3;
        float s0 = sc[wv][h][i][0], s1 = sc[wv][h][i][1];
        float s2 = sc[wv][h][i][2], s3 = sc[wv][h][i][3];
        float m = fmaxf(fmaxf(s0, s1), fmaxf(s2, s3));
        float e0 = expf(s0 - m), e1 = expf(s1 - m);
        float e2 = expf(s2 - m), e3 = expf(s3 - m);
        float inv = 1.f / (e0 + e1 + e2 + e3);
        sc[wv][h][i][0] = e0 * inv;
        sc[wv][h][i][1] = e1 * inv;
        sc[wv][h][i][2] = e2 * inv;
        sc[wv][h][i][3] = e3 * inv;
    }
    __syncthreads();

    const int h = lane >> 3;
#pragma unroll
    for (int i = 0; i < 4; ++i) {
        f32x4 a = {0.f, 0.f, 0.f, 0.f};
#pragma unroll
        for (int j = 0; j < 4; ++j) {
            const float p = sc[wv][h][i][j];
            const f32x4 v = *(const f32x4*)(&qf[wv][j][512 + lane * 4]);
#pragma unroll
            for (int q = 0; q < 4; ++q) a[q] += p * v[q];
        }
        bf16x4 o;
#pragma unroll
        for (int q = 0; q < 4; ++q) o[q] = (bf16)a[q];
        *(bf16x4*)(SA + (size_t)(s * 4 + i) * 256 + lane * 4) = o;
    }
}

// --------------------------------------------------------------------------
// out[b][c][hw] = sum_e (mean_cam X[p*4+cam][e]) * Wout[c][e] + bout[c]
// --------------------------------------------------------------------------
__global__ __launch_bounds__(256) void out_proj_k(const bf16* __restrict__ X,
                                                  const float* __restrict__ Wout,
                                                  const float* __restrict__ bout,
                                                  float* __restrict__ out)
{
    __shared__ float fused[16][260];
    const int tid = threadIdx.x;
    const int p0  = blockIdx.x * 16;

#pragma unroll
    for (int it = 0; it < 16; ++it) {
        const int idx = it * 256 + tid;
        const int pix = idx >> 8, e = idx & 255;
        const size_t base = (size_t)(p0 + pix) * 1024 + e;
        const float s = (float)X[base] + (float)X[base + 256] +
                        (float)X[base + 512] + (float)X[base + 768];
        fused[pix][e] = s * 0.25f;
    }
    __syncthreads();

    const int pix = tid & 15;
    const int c0  = tid >> 4;
    const int p   = p0 + pix;
    const int b   = p / 9216;
    const int hw  = p % 9216;
#pragma unroll
    for (int it = 0; it < 4; ++it) {
        const int c = it * 16 + c0;
        const float* w = Wout + c * 256;
        float acc = bout[c];
#pragma unroll 8
        for (int e = 0; e < 256; ++e) acc += fused[pix][e] * w[e];
        out[((size_t)b * 64 + c) * 9216 + hw] = acc;
    }
}

// --------------------------------------------------------------------------
extern "C" void kernel_launch(void* const* d_in, const int* in_sizes, int n_in,
                              void* d_out, int out_size, void* d_ws, size_t ws_size,
                              hipStream_t stream)
{
    const float* features = (const float*)d_in[0];
    const float* Wp   = (const float*)d_in[1];
    const float* bp   = (const float*)d_in[2];
    const float* Wqkv = (const float*)d_in[3];
    const float* bqkv = (const float*)d_in[4];
    const float* Wo   = (const float*)d_in[5];
    const float* bo   = (const float*)d_in[6];
    const float* W1   = (const float*)d_in[7];
    const float* b1   = (const float*)d_in[8];
    const float* W2   = (const float*)d_in[9];
    const float* b2   = (const float*)d_in[10];
    const float* g1   = (const float*)d_in[11];
    const float* be1  = (const float*)d_in[12];
    const float* g2   = (const float*)d_in[13];
    const float* be2  = (const float*)d_in[14];
    const float* Wout = (const float*)d_in[15];
    const float* bout = (const float*)d_in[16];
    float* out = (float*)d_out;

    char* ws = (char*)d_ws;
    bf16* X   = (bf16*)(ws);                    // 73728*256
    bf16* QKV = (bf16*)(ws + 37748736ull);      // 73728*768
    bf16* SAb = (bf16*)(ws + 150994944ull);     // 73728*256
    bf16* Xf  = (bf16*)(ws + 188743680ull);     // 73728*64
    bf16* WpB = (bf16*)(ws + 198180864ull);     // 256*64
    bf16* Wb  = (bf16*)(ws + 226492416ull);     // packed bf16 weights

    bf16* WqkvB = Wb;                  // 2 x 768*256
    bf16* WoB   = Wb + 393216;         // 2 x 256*256
    bf16* W1B   = Wb + 524288;         // 2 x 1024*256
    bf16* W2B   = Wb + 1048576;        // 2 x 256*1024

    pack_all_k<<<6208, 256, 0, stream>>>(Wqkv, Wo, W1, W2, Wp,
                                         WqkvB, WoB, W1B, W2B, WpB);

    feat_pack_k<<<dim3(144, 8), 256, 0, stream>>>(features, Xf);
    gemm_bt<false><<<dim3(2, 576), 256, 0, stream>>>(Xf, WpB, bp, X, 256, 64);

    for (int l = 0; l < 2; ++l) {
        gemm_bt<false><<<dim3(6, 576), 256, 0, stream>>>(
            X, WqkvB + l * 196608, bqkv + l * 768, QKV, 768, 256);
        attention_k<<<4608, 256, 0, stream>>>(QKV, SAb);
        gemm_ln_k<<<576, 256, 0, stream>>>(
            SAb, WoB + l * 65536, bo + l * 256, X,
            g1 + l * 256, be1 + l * 256, X, 256);
        ffn_fused_k<<<1152, 256, 0, stream>>>(
            X, W1B + l * 262144, b1 + l * 1024,
            W2B + l * 262144, b2 + l * 256,
            g2 + l * 256, be2 + l * 256, X);
    }

    out_proj_k<<<1152, 256, 0, stream>>>(X, Wout, bout, out);
}

// Round 9
// 848.610 us; speedup vs baseline: 1.5046x; 1.5046x over previous
//
#include <hip/hip_runtime.h>
#include <cstdint>
#include <cstddef>

// ---------------------------------------------------------------------------
// TransformerMultiViewFusion (MI355X / gfx950), round 9.
//
//  R9: revert R8's two-hop staging (rp[] was address-taken -> scratch: 551MB
//  WRITE_SIZE). ffn_fused v5 on top of R7:
//   * phase-A A-operand held in registers: xa[2][8] bf16x8 (64 VGPR, all
//     static indices). No Xs LDS buffer; no phase-A af LDS reads.
//   * 32KB ping-pong weight stages (W1 halves 128hx128k, W2 halves 256nx64k,
//     R5-proven swizzles): 4 barriers/hc instead of 8, 32 MFMA per barrier.
//   * residual read from global in the epilogue.
//  LDS: Ts 16KB (red aliases) + 2x32KB stage = 80KB -> 2 blocks/CU.
//
//  Workspace: X@0 | QKV@37748736 | SA@150994944 | Xf@188743680 |
//             WpB@198180864 | Wb@226492416
// ---------------------------------------------------------------------------

typedef __bf16 bf16;
typedef __bf16 bf16x8 __attribute__((ext_vector_type(8)));
typedef __bf16 bf16x4 __attribute__((ext_vector_type(4)));
typedef float  f32x4  __attribute__((ext_vector_type(4)));

__device__ __forceinline__ void async_copy16(const void* g, void* l)
{
    __builtin_amdgcn_global_load_lds(
        (__attribute__((address_space(1))) void*)g,
        (__attribute__((address_space(3))) void*)l,
        16, 0, 0);
}

// --------------------------------------------------------------------------
// all 5 weight packs in one launch. 1589248 = 6208*256 exactly.
// --------------------------------------------------------------------------
__global__ void pack_all_k(const float* __restrict__ s0, const float* __restrict__ s1,
                           const float* __restrict__ s2, const float* __restrict__ s3,
                           const float* __restrict__ s4,
                           bf16* __restrict__ d0, bf16* __restrict__ d1,
                           bf16* __restrict__ d2, bf16* __restrict__ d3,
                           bf16* __restrict__ d4)
{
    const int i = blockIdx.x * 256 + threadIdx.x;
    if (i < 393216)       d0[i] = (bf16)s0[i];
    else if (i < 524288)  d1[i - 393216] = (bf16)s1[i - 393216];
    else if (i < 1048576) d2[i - 524288] = (bf16)s2[i - 524288];
    else if (i < 1572864) d3[i - 1048576] = (bf16)s3[i - 1048576];
    else                  d4[i - 1572864] = (bf16)s4[i - 1572864];
}

// --------------------------------------------------------------------------
// feat transpose-pack: Xf[t][c] = (bf16)feat[cam][b][c][hw]
// --------------------------------------------------------------------------
__global__ __launch_bounds__(256) void feat_pack_k(const float* __restrict__ feat,
                                                   bf16* __restrict__ Xf)
{
    __shared__ float ft[64][68];

    const int tid  = threadIdx.x;
    const int camb = blockIdx.y;
    const int cam  = camb >> 1;
    const int b    = camb & 1;
    const int hw0  = blockIdx.x * 64;

    const float* fb = feat + (size_t)camb * 64 * 9216 + hw0;
#pragma unroll
    for (int rep = 0; rep < 16; ++rep) {
        const int idx = rep * 256 + tid;
        const int c = idx >> 6, p = idx & 63;
        ft[p][c] = fb[(size_t)c * 9216 + p];
    }
    __syncthreads();

    const int pbase = b * 9216 + hw0;
#pragma unroll
    for (int rep = 0; rep < 2; ++rep) {
        const int idx = rep * 256 + tid;
        const int p = idx >> 3, cc = idx & 7;
        const f32x4 a = *(const f32x4*)(&ft[p][cc * 8]);
        const f32x4 c4 = *(const f32x4*)(&ft[p][cc * 8 + 4]);
        bf16x8 v;
#pragma unroll
        for (int i = 0; i < 4; ++i) { v[i] = (bf16)a[i]; v[4 + i] = (bf16)c4[i]; }
        const size_t t = (size_t)(pbase + p) * 4 + cam;
        *(bf16x8*)(Xf + t * 64 + cc * 8) = v;
    }
}

// --------------------------------------------------------------------------
// GEMM-BT: C[M,N] = A[M,K] @ B[N,K]^T + bias[N], bf16 in/out. 128x128 tile.
// --------------------------------------------------------------------------
template <bool RELU>
__global__ __launch_bounds__(256, 2) void gemm_bt(
    const bf16* __restrict__ A, const bf16* __restrict__ B,
    const float* __restrict__ bias, bf16* __restrict__ C,
    int N, int K)
{
    __shared__ __align__(16) bf16 As[128 * 64];
    __shared__ __align__(16) bf16 Bs[128 * 64];

    const int tid  = threadIdx.x;
    const int lane = tid & 63;
    const int wv   = tid >> 6;
    const int wm   = wv >> 1;
    const int wn   = wv & 1;
    const int bm   = blockIdx.y * 128;
    const int bn   = blockIdx.x * 128;

    const int r8  = lane >> 3;
    const int p8  = lane & 7;
    const int gch = p8 ^ r8;

    const int quad = lane >> 4;
    const int l16  = lane & 15;

    f32x4 acc[4][4] = {};

    for (int k0 = 0; k0 < K; k0 += 64) {
#pragma unroll
        for (int inst = 0; inst < 4; ++inst) {
            const int row = wv * 32 + inst * 8 + r8;
            const bf16* ga = A + (size_t)(bm + row) * K + (k0 + gch * 8);
            const bf16* gb = B + (size_t)(bn + row) * K + (k0 + gch * 8);
            async_copy16(ga, (char*)As + (wv * 4 + inst) * 1024);
            async_copy16(gb, (char*)Bs + (wv * 4 + inst) * 1024);
        }
        __syncthreads();

#pragma unroll
        for (int kk = 0; kk < 2; ++kk) {
            bf16x8 af[4], bfr[4];
            const int lch = kk * 4 + quad;
#pragma unroll
            for (int i = 0; i < 4; ++i) {
                const int m = wm * 64 + i * 16 + l16;
                af[i] = *(const bf16x8*)((const char*)As + (m * 8 + (lch ^ (m & 7))) * 16);
                const int n = wn * 64 + i * 16 + l16;
                bfr[i] = *(const bf16x8*)((const char*)Bs + (n * 8 + (lch ^ (n & 7))) * 16);
            }
#pragma unroll
            for (int i = 0; i < 4; ++i)
#pragma unroll
                for (int j = 0; j < 4; ++j)
                    acc[i][j] = __builtin_amdgcn_mfma_f32_16x16x32_bf16(
                        af[i], bfr[j], acc[i][j], 0, 0, 0);
        }
        __syncthreads();
    }

#pragma unroll
    for (int j = 0; j < 4; ++j) {
        const int n = bn + wn * 64 + j * 16 + l16;
        const float bv = bias[n];
#pragma unroll
        for (int i = 0; i < 4; ++i) {
            const int mb = bm + wm * 64 + i * 16 + quad * 4;
#pragma unroll
            for (int r = 0; r < 4; ++r) {
                float v = acc[i][j][r] + bv;
                if (RELU) v = fmaxf(v, 0.f);
                C[(size_t)(mb + r) * N + n] = (bf16)v;
            }
        }
    }
}

// --------------------------------------------------------------------------
// GEMM-BT + bias + residual + LayerNorm (Wo path, K=256). 128x256 tile.
// --------------------------------------------------------------------------
__global__ __launch_bounds__(256, 2) void gemm_ln_k(
    const bf16* __restrict__ A, const bf16* __restrict__ B,
    const float* __restrict__ bias, const bf16* __restrict__ Xres,
    const float* __restrict__ gam, const float* __restrict__ bet,
    bf16* __restrict__ Xout, int K)
{
    __shared__ __align__(16) bf16 S[24576];
    __shared__ float2 red[128][2];

    const int tid  = threadIdx.x;
    const int lane = tid & 63;
    const int wv   = tid >> 6;
    const int wm   = wv >> 1;
    const int wn   = wv & 1;
    const int bm   = blockIdx.x * 128;
    const int quad = lane >> 4;
    const int l16  = lane & 15;

    f32x4 acc[4][8] = {};

    for (int k0 = 0; k0 < K; k0 += 64) {
#pragma unroll
        for (int s = 0; s < 12; ++s) {
            const int L   = s * 256 + tid;
            const int row = L >> 3;
            const int gch = (L & 7) ^ (row & 7);
            const bf16* g = (row < 128)
                ? A + (size_t)(bm + row) * K + (k0 + gch * 8)
                : B + (size_t)(row - 128) * K + (k0 + gch * 8);
            async_copy16(g, (char*)S + (size_t)L * 16);
        }
        __syncthreads();

#pragma unroll
        for (int kk = 0; kk < 2; ++kk) {
            const int lch = kk * 4 + quad;
            bf16x8 af[4], bfr[8];
#pragma unroll
            for (int i = 0; i < 4; ++i) {
                const int m = wm * 64 + i * 16 + l16;
                af[i] = *(const bf16x8*)((const char*)S + (m * 8 + (lch ^ (m & 7))) * 16);
            }
#pragma unroll
            for (int j = 0; j < 8; ++j) {
                const int n = wn * 128 + j * 16 + l16;
                bfr[j] = *(const bf16x8*)((const char*)S + ((128 + n) * 8 + (lch ^ (n & 7))) * 16);
            }
#pragma unroll
            for (int i = 0; i < 4; ++i)
#pragma unroll
                for (int j = 0; j < 8; ++j)
                    acc[i][j] = __builtin_amdgcn_mfma_f32_16x16x32_bf16(
                        af[i], bfr[j], acc[i][j], 0, 0, 0);
        }
        __syncthreads();
    }

    float bv[8], gv[8], bev[8];
#pragma unroll
    for (int j = 0; j < 8; ++j) {
        const int n = wn * 128 + j * 16 + l16;
        bv[j] = bias[n]; gv[j] = gam[n]; bev[j] = bet[n];
    }

#pragma unroll
    for (int i = 0; i < 4; ++i) {
#pragma unroll
        for (int r = 0; r < 4; ++r) {
            const int rl  = wm * 64 + i * 16 + quad * 4 + r;
            const size_t row = (size_t)(bm + rl);
            float s1 = 0.f, s2 = 0.f;
#pragma unroll
            for (int j = 0; j < 8; ++j) {
                const int n = wn * 128 + j * 16 + l16;
                const float v = acc[i][j][r] + bv[j] + (float)Xres[row * 256 + n];
                acc[i][j][r] = v;
                s1 += v; s2 += v * v;
            }
#pragma unroll
            for (int off = 1; off < 16; off <<= 1) {
                s1 += __shfl_xor(s1, off, 64);
                s2 += __shfl_xor(s2, off, 64);
            }
            if (l16 == 0) red[rl][wn] = make_float2(s1, s2);
        }
    }
    __syncthreads();

#pragma unroll
    for (int i = 0; i < 4; ++i) {
#pragma unroll
        for (int r = 0; r < 4; ++r) {
            const int rl = wm * 64 + i * 16 + quad * 4 + r;
            const float2 p0 = red[rl][0], p1 = red[rl][1];
            const float mu  = (p0.x + p1.x) * (1.f / 256.f);
            const float ex2 = (p0.y + p1.y) * (1.f / 256.f);
            const float rstd = rsqrtf(fmaxf(ex2 - mu * mu, 0.f) + 1e-5f);
            const size_t row = (size_t)(bm + rl);
#pragma unroll
            for (int j = 0; j < 8; ++j) {
                const int n = wn * 128 + j * 16 + l16;
                Xout[row * 256 + n] = (bf16)((acc[i][j][r] - mu) * rstd * gv[j] + bev[j]);
            }
        }
    }
}

// --------------------------------------------------------------------------
// ffn 32KB stage, step st (0..31): hc = st>>2, ps = st&3.
//  ps<2 : W1 half [128 h][128 k], 16 chunks/row, slot = (c&8)|((c^row)&7)
//  ps>=2: W2 half [256 n][64 k],   8 chunks/row, slot = c ^ (row&7)
// All via global_load_lds (wave-uniform dest, no VGPR arrays -> no scratch).
// --------------------------------------------------------------------------
__device__ __forceinline__ void ffn_stage32(int st, const bf16* __restrict__ W1,
                                            const bf16* __restrict__ W2,
                                            char* stg, int tid)
{
    char* buf = stg + (size_t)(st & 1) * 32768;
    const int hc = st >> 2;
    const int ps = st & 3;
    if (ps < 2) {
#pragma unroll
        for (int it = 0; it < 8; ++it) {
            const int L = it * 256 + tid;
            const int row = L >> 4, pslot = L & 15;
            const int c = (pslot & 8) | ((pslot ^ row) & 7);
            async_copy16(W1 + (size_t)(hc * 128 + row) * 256 + ps * 128 + c * 8,
                         buf + (size_t)L * 16);
        }
    } else {
#pragma unroll
        for (int it = 0; it < 8; ++it) {
            const int L = it * 256 + tid;
            const int row = L >> 3, pslot = L & 7;
            const int c = pslot ^ (row & 7);
            async_copy16(W2 + (size_t)row * 1024 + hc * 128 + (ps - 2) * 64 + c * 8,
                         buf + (size_t)L * 16);
        }
    }
}

// --------------------------------------------------------------------------
// Fused FFN v5: Xout = LN(X + relu(X@W1^T+b1)@W2^T + b2)*gam + bet, in-place.
// 64-row tile, grid 1152, 4 waves 2x2. 8 hidden chunks of 128.
// A-operand (X) in registers xa[2][8] (static indices only!). Weight stages
// 2x32KB ping-pong via global_load_lds; 4 barriers/hc, 32 MFMA/barrier.
// LDS: Ts 16KB (red[] aliases) + 64KB stage = 80KB -> 2 blocks/CU.
// --------------------------------------------------------------------------
__global__ __launch_bounds__(256, 2) void ffn_fused_k(
    const bf16* __restrict__ X,
    const bf16* __restrict__ W1, const float* __restrict__ b1,
    const bf16* __restrict__ W2, const float* __restrict__ b2,
    const float* __restrict__ gam, const float* __restrict__ bet,
    bf16* __restrict__ Xout)
{
    __shared__ __align__(16) char smem[81920];
    bf16* Ts = (bf16*)smem;                              // 64 x 128 (16 slots/row)
    float2 (*red)[2] = (float2 (*)[2])(void*)smem;       // aliases Ts
    char* stg = smem + 16384;                            // 2 x 32KB

    const int tid  = threadIdx.x;
    const int lane = tid & 63;
    const int wv   = tid >> 6;
    const int wm   = wv >> 1;
    const int wn   = wv & 1;
    const int quad = lane >> 4;
    const int l16  = lane & 15;
    const int bm   = blockIdx.x * 64;

    // A-operand preload: xa[i][c] = X[bm + wm*32 + i*16 + l16][c*32 + quad*8 ..+8]
    bf16x8 xa[2][8];
#pragma unroll
    for (int i = 0; i < 2; ++i)
#pragma unroll
        for (int c = 0; c < 8; ++c)
            xa[i][c] = *(const bf16x8*)(X + (size_t)(bm + wm * 32 + i * 16 + l16) * 256
                                          + c * 32 + quad * 8);

    ffn_stage32(0, W1, W2, stg, tid);
    __syncthreads();

    f32x4 acc2[2][8] = {};

#pragma unroll 1
    for (int hc = 0; hc < 8; ++hc) {
        f32x4 accA[2][4] = {};

        // ---- phase A: accA = X @ W1c^T, 2 half-steps of 128k
#pragma unroll
        for (int half = 0; half < 2; ++half) {
            const int st = hc * 4 + half;
            ffn_stage32(st + 1, W1, W2, stg, tid);
            const char* cur = stg + (size_t)(st & 1) * 32768;
#pragma unroll
            for (int kk = 0; kk < 4; ++kk) {
                const int lch = kk * 4 + quad;       // chunk in staged half (0..15)
                bf16x8 bfr[4];
#pragma unroll
                for (int j = 0; j < 4; ++j) {
                    const int n  = wn * 64 + j * 16 + l16;
                    const int sl = (lch & 8) | ((lch ^ n) & 7);
                    bfr[j] = *(const bf16x8*)(cur + (n * 16 + sl) * 16);
                }
#pragma unroll
                for (int i = 0; i < 2; ++i)
#pragma unroll
                    for (int j = 0; j < 4; ++j)
                        accA[i][j] = __builtin_amdgcn_mfma_f32_16x16x32_bf16(
                            xa[i][half * 4 + kk], bfr[j], accA[i][j], 0, 0, 0);
            }
            if (half == 1) {
                // Ts = relu(accA + b1)   (prev hc's readers done at last barrier)
#pragma unroll
                for (int j = 0; j < 4; ++j) {
                    const int h  = wn * 64 + j * 16 + l16;
                    const float bb = b1[hc * 128 + h];
                    const int g  = h >> 3;
#pragma unroll
                    for (int i = 0; i < 2; ++i)
#pragma unroll
                        for (int r = 0; r < 4; ++r) {
                            const int m  = wm * 32 + i * 16 + quad * 4 + r;
                            const int sl = (g & 8) | ((g ^ m) & 7);
                            const float v = fmaxf(accA[i][j][r] + bb, 0.f);
                            *((bf16*)((char*)Ts + (m * 16 + sl) * 16 + (h & 7) * 2)) = (bf16)v;
                        }
                }
            }
            __syncthreads();
        }

        // ---- phase B: acc2 += Ts @ W2c^T, 2 half-steps of 64 h
#pragma unroll
        for (int half = 0; half < 2; ++half) {
            const int st = hc * 4 + 2 + half;
            if (st + 1 < 32) ffn_stage32(st + 1, W1, W2, stg, tid);
            const char* cur = stg + (size_t)(st & 1) * 32768;
#pragma unroll
            for (int kk = 0; kk < 2; ++kk) {
                const int tcg = half * 8 + kk * 4 + quad;   // Ts chunk 0..15
                bf16x8 af[2];
#pragma unroll
                for (int i = 0; i < 2; ++i) {
                    const int m  = wm * 32 + i * 16 + l16;
                    const int sl = (tcg & 8) | ((tcg ^ m) & 7);
                    af[i] = *(const bf16x8*)((const char*)Ts + (m * 16 + sl) * 16);
                }
                bf16x8 bfr[8];
#pragma unroll
                for (int j = 0; j < 8; ++j) {
                    const int n  = wn * 128 + j * 16 + l16;
                    const int tl = kk * 4 + quad;           // chunk in W2 half (0..7)
                    const int sl = tl ^ (n & 7);
                    bfr[j] = *(const bf16x8*)(cur + (n * 8 + sl) * 16);
                }
#pragma unroll
                for (int i = 0; i < 2; ++i)
#pragma unroll
                    for (int j = 0; j < 8; ++j)
                        acc2[i][j] = __builtin_amdgcn_mfma_f32_16x16x32_bf16(
                            af[i], bfr[j], acc2[i][j], 0, 0, 0);
            }
            __syncthreads();
        }
    }

    // ---- epilogue: bias + residual (global) + LayerNorm (red aliases Ts)
    float bv[8], gv[8], bev[8];
#pragma unroll
    for (int j = 0; j < 8; ++j) {
        const int n = wn * 128 + j * 16 + l16;
        bv[j] = b2[n]; gv[j] = gam[n]; bev[j] = bet[n];
    }

#pragma unroll
    for (int i = 0; i < 2; ++i) {
#pragma unroll
        for (int r = 0; r < 4; ++r) {
            const int rl = wm * 32 + i * 16 + quad * 4 + r;
            const size_t row = (size_t)(bm + rl);
            float s1 = 0.f, s2 = 0.f;
#pragma unroll
            for (int j = 0; j < 8; ++j) {
                const int n = wn * 128 + j * 16 + l16;
                const float v = acc2[i][j][r] + bv[j] + (float)X[row * 256 + n];
                acc2[i][j][r] = v;
                s1 += v; s2 += v * v;
            }
#pragma unroll
            for (int off = 1; off < 16; off <<= 1) {
                s1 += __shfl_xor(s1, off, 64);
                s2 += __shfl_xor(s2, off, 64);
            }
            if (l16 == 0) red[rl][wn] = make_float2(s1, s2);
        }
    }
    __syncthreads();

#pragma unroll
    for (int i = 0; i < 2; ++i) {
#pragma unroll
        for (int r = 0; r < 4; ++r) {
            const int rl = wm * 32 + i * 16 + quad * 4 + r;
            const float2 p0 = red[rl][0], p1 = red[rl][1];
            const float mu  = (p0.x + p1.x) * (1.f / 256.f);
            const float ex2 = (p0.y + p1.y) * (1.f / 256.f);
            const float rstd = rsqrtf(fmaxf(ex2 - mu * mu, 0.f) + 1e-5f);
            const size_t row = (size_t)(bm + rl);
#pragma unroll
            for (int j = 0; j < 8; ++j) {
                const int n = wn * 128 + j * 16 + l16;
                Xout[row * 256 + n] = (bf16)((acc2[i][j][r] - mu) * rstd * gv[j] + bev[j]);
            }
        }
    }
}

// --------------------------------------------------------------------------
// attention v2: per sequence (4 tokens), 8 heads x dh=32, softmax over 4.
// --------------------------------------------------------------------------
__global__ __launch_bounds__(256) void attention_k(const bf16* __restrict__ QKV,
                                                   bf16* __restrict__ SA)
{
    __shared__ float qf[4][4][768];
    __shared__ float sc[4][8][4][4];

    const int tid  = threadIdx.x;
    const int wv   = tid >> 6;
    const int lane = tid & 63;
    const int s    = blockIdx.x * 4 + wv;

    const bf16* base = QKV + (size_t)s * 4 * 768;
#pragma unroll
    for (int it = 0; it < 6; ++it) {
        const int idx = it * 64 + lane;
        const bf16x8 v = *(const bf16x8*)(base + idx * 8);
        const int tok = idx / 96;
        const int e   = (idx % 96) * 8;
        f32x4 f0, f1;
#pragma unroll
        for (int i = 0; i < 4; ++i) { f0[i] = (float)v[i]; f1[i] = (float)v[4 + i]; }
        *(f32x4*)(&qf[wv][tok][e])     = f0;
        *(f32x4*)(&qf[wv][tok][e + 4]) = f1;
    }
    __syncthreads();

#pragma unroll
    for (int rep = 0; rep < 2; ++rep) {
        const int t = rep * 64 + lane;
        const int h = t >> 4, i = (t >> 2) & 3, j = t & 3;
        const float* q = &qf[wv][i][h * 32];
        const float* k = &qf[wv][j][256 + h * 32];
        float a = 0.f;
#pragma unroll
        for (int dd = 0; dd < 32; ++dd) {
            const int d = (dd + lane) & 31;
            a += q[d] * k[d];
        }
        sc[wv][h][i][j] = a * 0.17677669529663687f;
    }
    __syncthreads();

    if (lane < 32) {
        const int h = lane >> 2, i = lane & 3;
        float s0 = sc[wv][h][i][0], s1 = sc[wv][h][i][1];
        float s2 = sc[wv][h][i][2], s3 = sc[wv][h][i][3];
        float m = fmaxf(fmaxf(s0, s1), fmaxf(s2, s3));
        float e0 = expf(s0 - m), e1 = expf(s1 - m);
        float e2 = expf(s2 - m), e3 = expf(s3 - m);
        float inv = 1.f / (e0 + e1 + e2 + e3);
        sc[wv][h][i][0] = e0 * inv;
        sc[wv][h][i][1] = e1 * inv;
        sc[wv][h][i][2] = e2 * inv;
        sc[wv][h][i][3] = e3 * inv;
    }
    __syncthreads();

    const int h = lane >> 3;
#pragma unroll
    for (int i = 0; i < 4; ++i) {
        f32x4 a = {0.f, 0.f, 0.f, 0.f};
#pragma unroll
        for (int j = 0; j < 4; ++j) {
            const float p = sc[wv][h][i][j];
            const f32x4 v = *(const f32x4*)(&qf[wv][j][512 + lane * 4]);
#pragma unroll
            for (int q = 0; q < 4; ++q) a[q] += p * v[q];
        }
        bf16x4 o;
#pragma unroll
        for (int q = 0; q < 4; ++q) o[q] = (bf16)a[q];
        *(bf16x4*)(SA + (size_t)(s * 4 + i) * 256 + lane * 4) = o;
    }
}

// --------------------------------------------------------------------------
// out[b][c][hw] = sum_e (mean_cam X[p*4+cam][e]) * Wout[c][e] + bout[c]
// --------------------------------------------------------------------------
__global__ __launch_bounds__(256) void out_proj_k(const bf16* __restrict__ X,
                                                  const float* __restrict__ Wout,
                                                  const float* __restrict__ bout,
                                                  float* __restrict__ out)
{
    __shared__ float fused[16][260];
    const int tid = threadIdx.x;
    const int p0  = blockIdx.x * 16;

#pragma unroll
    for (int it = 0; it < 16; ++it) {
        const int idx = it * 256 + tid;
        const int pix = idx >> 8, e = idx & 255;
        const size_t base = (size_t)(p0 + pix) * 1024 + e;
        const float s = (float)X[base] + (float)X[base + 256] +
                        (float)X[base + 512] + (float)X[base + 768];
        fused[pix][e] = s * 0.25f;
    }
    __syncthreads();

    const int pix = tid & 15;
    const int c0  = tid >> 4;
    const int p   = p0 + pix;
    const int b   = p / 9216;
    const int hw  = p % 9216;
#pragma unroll
    for (int it = 0; it < 4; ++it) {
        const int c = it * 16 + c0;
        const float* w = Wout + c * 256;
        float acc = bout[c];
#pragma unroll 8
        for (int e = 0; e < 256; ++e) acc += fused[pix][e] * w[e];
        out[((size_t)b * 64 + c) * 9216 + hw] = acc;
    }
}

// --------------------------------------------------------------------------
extern "C" void kernel_launch(void* const* d_in, const int* in_sizes, int n_in,
                              void* d_out, int out_size, void* d_ws, size_t ws_size,
                              hipStream_t stream)
{
    const float* features = (const float*)d_in[0];
    const float* Wp   = (const float*)d_in[1];
    const float* bp   = (const float*)d_in[2];
    const float* Wqkv = (const float*)d_in[3];
    const float* bqkv = (const float*)d_in[4];
    const float* Wo   = (const float*)d_in[5];
    const float* bo   = (const float*)d_in[6];
    const float* W1   = (const float*)d_in[7];
    const float* b1   = (const float*)d_in[8];
    const float* W2   = (const float*)d_in[9];
    const float* b2   = (const float*)d_in[10];
    const float* g1   = (const float*)d_in[11];
    const float* be1  = (const float*)d_in[12];
    const float* g2   = (const float*)d_in[13];
    const float* be2  = (const float*)d_in[14];
    const float* Wout = (const float*)d_in[15];
    const float* bout = (const float*)d_in[16];
    float* out = (float*)d_out;

    char* ws = (char*)d_ws;
    bf16* X   = (bf16*)(ws);                    // 73728*256
    bf16* QKV = (bf16*)(ws + 37748736ull);      // 73728*768
    bf16* SAb = (bf16*)(ws + 150994944ull);     // 73728*256
    bf16* Xf  = (bf16*)(ws + 188743680ull);     // 73728*64
    bf16* WpB = (bf16*)(ws + 198180864ull);     // 256*64
    bf16* Wb  = (bf16*)(ws + 226492416ull);     // packed bf16 weights

    bf16* WqkvB = Wb;                  // 2 x 768*256
    bf16* WoB   = Wb + 393216;         // 2 x 256*256
    bf16* W1B   = Wb + 524288;         // 2 x 1024*256
    bf16* W2B   = Wb + 1048576;        // 2 x 256*1024

    pack_all_k<<<6208, 256, 0, stream>>>(Wqkv, Wo, W1, W2, Wp,
                                         WqkvB, WoB, W1B, W2B, WpB);

    feat_pack_k<<<dim3(144, 8), 256, 0, stream>>>(features, Xf);
    gemm_bt<false><<<dim3(2, 576), 256, 0, stream>>>(Xf, WpB, bp, X, 256, 64);

    for (int l = 0; l < 2; ++l) {
        gemm_bt<false><<<dim3(6, 576), 256, 0, stream>>>(
            X, WqkvB + l * 196608, bqkv + l * 768, QKV, 768, 256);
        attention_k<<<4608, 256, 0, stream>>>(QKV, SAb);
        gemm_ln_k<<<576, 256, 0, stream>>>(
            SAb, WoB + l * 65536, bo + l * 256, X,
            g1 + l * 256, be1 + l * 256, X, 256);
        ffn_fused_k<<<1152, 256, 0, stream>>>(
            X, W1B + l * 262144, b1 + l * 1024,
            W2B + l * 262144, b2 + l * 256,
            g2 + l * 256, be2 + l * 256, X);
    }

    out_proj_k<<<1152, 256, 0, stream>>>(X, Wout, bout, out);
}

// Round 10
// 847.498 us; speedup vs baseline: 1.5066x; 1.0013x over previous
//
#include <hip/hip_runtime.h>
#include <cstdint>
#include <cstddef>

// ---------------------------------------------------------------------------
// TransformerMultiViewFusion (MI355X / gfx950), round 10.
//
//  R10: weights pre-packed to MFMA fragment order (frag[nt][kc][lane] 16B,
//  1KB contiguous per fragment) -> B-operands load straight global->VGPR,
//  coalesced, L2-resident, NO staging barriers (the R5-R9 bottleneck).
//  All GEMMs restructured "A-resident-in-LDS, B-from-fragments":
//   * gemm_a<K>: A-tile 128xK staged once (1 barrier/block), kk-loop has
//     zero barriers. Replaces gemm_bt.
//   * gemm_ln_a: same + LN epilogue (Wo path).
//   * ffn_fused v6: Xs 32K + Ts 16K = 48KB LDS (3 blocks/CU), barriers only
//     around the Ts transpose (2/hc = 17/block vs R7's 72).
//  Accumulators stay in MFMA acc regs; operands transient (R8/R9 lesson:
//  no address-taken register arrays -> no scratch).
//
//  Workspace: X@0 | QKV@37748736 | SA@150994944 | Xf@188743680 |
//             WpF@198180864 | Wfrag@226492416 (same sizes, fragment order)
// ---------------------------------------------------------------------------

typedef __bf16 bf16;
typedef __bf16 bf16x8 __attribute__((ext_vector_type(8)));
typedef __bf16 bf16x4 __attribute__((ext_vector_type(4)));
typedef float  f32x4  __attribute__((ext_vector_type(4)));

__device__ __forceinline__ void async_copy16(const void* g, void* l)
{
    __builtin_amdgcn_global_load_lds(
        (__attribute__((address_space(1))) void*)g,
        (__attribute__((address_space(3))) void*)l,
        16, 0, 0);
}

// --------------------------------------------------------------------------
// Pack all weights fp32 -> bf16 MFMA-fragment layout.
// frag entry e of a [N x K] matrix: nt = e/((K/32)*64); kc = (e%..)>>6;
// lane = e&63; holds W[nt*16 + (lane&15)][kc*32 + (lane>>4)*8 .. +8].
// Entry ranges (16B entries): Wp 2048 | Wqkv 49152 | Wo 16384 | W1 65536 |
// W2 65536 -> 198656 total = 776 blocks.
// --------------------------------------------------------------------------
__global__ void pack_frag_k(const float* __restrict__ Wp, const float* __restrict__ Wqkv,
                            const float* __restrict__ Wo, const float* __restrict__ W1,
                            const float* __restrict__ W2,
                            bf16* __restrict__ WpF, bf16* __restrict__ WqkvF,
                            bf16* __restrict__ WoF, bf16* __restrict__ W1F,
                            bf16* __restrict__ W2F)
{
    const int g = blockIdx.x * 256 + threadIdx.x;
    const float* src; bf16* dst; int K, e;
    if (g < 2048)        { src = Wp;  dst = WpF;  K = 64;  e = g; }
    else if (g < 51200)  { int r = g - 2048;  int l = r / 24576; e = r % 24576;
                           src = Wqkv + l * 196608; dst = WqkvF + l * 196608; K = 256; }
    else if (g < 67584)  { int r = g - 51200; int l = r / 8192;  e = r % 8192;
                           src = Wo + l * 65536;   dst = WoF + l * 65536;   K = 256; }
    else if (g < 133120) { int r = g - 67584; int l = r / 32768; e = r % 32768;
                           src = W1 + l * 262144;  dst = W1F + l * 262144;  K = 256; }
    else                 { int r = g - 133120; int l = r / 32768; e = r % 32768;
                           src = W2 + l * 262144;  dst = W2F + l * 262144;  K = 1024; }

    const int perNT = (K >> 5) << 6;          // (K/32)*64, always pow2 here
    const int nt   = e / perNT;
    const int rem  = e % perNT;
    const int kc   = rem >> 6;
    const int lane = rem & 63;
    const int row  = nt * 16 + (lane & 15);
    const int col  = kc * 32 + (lane >> 4) * 8;
    bf16x8 v;
#pragma unroll
    for (int q = 0; q < 8; ++q) v[q] = (bf16)src[(size_t)row * K + col + q];
    *(bf16x8*)(dst + (size_t)e * 8) = v;
}

// --------------------------------------------------------------------------
// feat transpose-pack: Xf[t][c] = (bf16)feat[cam][b][c][hw]
// --------------------------------------------------------------------------
__global__ __launch_bounds__(256) void feat_pack_k(const float* __restrict__ feat,
                                                   bf16* __restrict__ Xf)
{
    __shared__ float ft[64][68];

    const int tid  = threadIdx.x;
    const int camb = blockIdx.y;
    const int cam  = camb >> 1;
    const int b    = camb & 1;
    const int hw0  = blockIdx.x * 64;

    const float* fb = feat + (size_t)camb * 64 * 9216 + hw0;
#pragma unroll
    for (int rep = 0; rep < 16; ++rep) {
        const int idx = rep * 256 + tid;
        const int c = idx >> 6, p = idx & 63;
        ft[p][c] = fb[(size_t)c * 9216 + p];
    }
    __syncthreads();

    const int pbase = b * 9216 + hw0;
#pragma unroll
    for (int rep = 0; rep < 2; ++rep) {
        const int idx = rep * 256 + tid;
        const int p = idx >> 3, cc = idx & 7;
        const f32x4 a = *(const f32x4*)(&ft[p][cc * 8]);
        const f32x4 c4 = *(const f32x4*)(&ft[p][cc * 8 + 4]);
        bf16x8 v;
#pragma unroll
        for (int i = 0; i < 4; ++i) { v[i] = (bf16)a[i]; v[4 + i] = (bf16)c4[i]; }
        const size_t t = (size_t)(pbase + p) * 4 + cam;
        *(bf16x8*)(Xf + t * 64 + cc * 8) = v;
    }
}

// --------------------------------------------------------------------------
// gemm_a<K,RELU>: C[M,Ntot] tile = A[M,K] @ Bfrag + bias. 128x128 tile.
// A staged once (1 barrier); B-fragments direct from global (coalesced 1KB).
// 4 waves 2x2, per wave 64x64 = acc[4][4]. kk-loop barrier-free.
// --------------------------------------------------------------------------
template <int K, bool RELU>
__global__ __launch_bounds__(256, 2) void gemm_a(
    const bf16* __restrict__ A, const bf16* __restrict__ Bf,
    const float* __restrict__ bias, bf16* __restrict__ C, int Ntot)
{
    __shared__ __align__(16) char As[128 * K * 2];
    constexpr int CPR = K / 8;                 // 16B chunks per row

    const int tid  = threadIdx.x;
    const int lane = tid & 63;
    const int wv   = tid >> 6;
    const int wm   = wv >> 1;
    const int wn   = wv & 1;
    const int bm   = blockIdx.y * 128;
    const int bn   = blockIdx.x * 128;
    const int nt0  = blockIdx.x * 8;
    const int quad = lane >> 4;
    const int l16  = lane & 15;

    // stage A once: 128 rows x CPR chunks, low-3-bit XOR swizzle
#pragma unroll
    for (int it = 0; it < K / 16; ++it) {
        const int L = it * 256 + tid;
        const int row = L / CPR, s = L % CPR;
        const int c = (s & ~7) | ((s ^ row) & 7);
        async_copy16(A + (size_t)(bm + row) * K + c * 8, As + (size_t)L * 16);
    }
    __syncthreads();

    f32x4 acc[4][4] = {};

#pragma unroll
    for (int kk = 0; kk < K / 32; ++kk) {
        bf16x8 af[4], bfr[4];
        const int gc = kk * 4 + quad;
#pragma unroll
        for (int i = 0; i < 4; ++i) {
            const int m  = wm * 64 + i * 16 + l16;
            const int sl = (gc & ~7) | ((gc ^ m) & 7);
            af[i] = *(const bf16x8*)(As + (size_t)(m * CPR + sl) * 16);
        }
#pragma unroll
        for (int j = 0; j < 4; ++j) {
            const int nt = nt0 + wn * 4 + j;
            bfr[j] = *(const bf16x8*)(Bf + ((size_t)(nt * (K / 32) + kk) * 64 + lane) * 8);
        }
#pragma unroll
        for (int i = 0; i < 4; ++i)
#pragma unroll
            for (int j = 0; j < 4; ++j)
                acc[i][j] = __builtin_amdgcn_mfma_f32_16x16x32_bf16(
                    af[i], bfr[j], acc[i][j], 0, 0, 0);
    }

#pragma unroll
    for (int j = 0; j < 4; ++j) {
        const int n = bn + wn * 64 + j * 16 + l16;
        const float bv = bias[n];
#pragma unroll
        for (int i = 0; i < 4; ++i) {
            const int mb = bm + wm * 64 + i * 16 + quad * 4;
#pragma unroll
            for (int r = 0; r < 4; ++r) {
                float v = acc[i][j][r] + bv;
                if (RELU) v = fmaxf(v, 0.f);
                C[(size_t)(mb + r) * Ntot + n] = (bf16)v;
            }
        }
    }
}

// --------------------------------------------------------------------------
// gemm_ln_a: Xout = LN(A@Bfrag + bias + Xres)*gam + bet. K=256, N=256.
// 128x256 tile (grid 576), waves 2x2, per wave 64x128 = acc[4][8].
// A staged once; B-fragments from global; LN epilogue as before.
// --------------------------------------------------------------------------
__global__ __launch_bounds__(256, 2) void gemm_ln_a(
    const bf16* __restrict__ A, const bf16* __restrict__ Bf,
    const float* __restrict__ bias, const bf16* __restrict__ Xres,
    const float* __restrict__ gam, const float* __restrict__ bet,
    bf16* __restrict__ Xout)
{
    __shared__ __align__(16) char As[128 * 256 * 2];   // 64KB
    __shared__ float2 red[128][2];

    const int tid  = threadIdx.x;
    const int lane = tid & 63;
    const int wv   = tid >> 6;
    const int wm   = wv >> 1;
    const int wn   = wv & 1;
    const int bm   = blockIdx.x * 128;
    const int quad = lane >> 4;
    const int l16  = lane & 15;

#pragma unroll
    for (int it = 0; it < 16; ++it) {
        const int L = it * 256 + tid;
        const int row = L >> 5, s = L & 31;
        const int c = (s & 24) | ((s ^ row) & 7);
        async_copy16(A + (size_t)(bm + row) * 256 + c * 8, As + (size_t)L * 16);
    }
    __syncthreads();

    f32x4 acc[4][8] = {};

#pragma unroll
    for (int kk = 0; kk < 8; ++kk) {
        bf16x8 af[4], bfr[8];
        const int gc = kk * 4 + quad;
#pragma unroll
        for (int i = 0; i < 4; ++i) {
            const int m  = wm * 64 + i * 16 + l16;
            const int sl = (gc & 24) | ((gc ^ m) & 7);
            af[i] = *(const bf16x8*)(As + (size_t)(m * 32 + sl) * 16);
        }
#pragma unroll
        for (int j = 0; j < 8; ++j) {
            const int nt = wn * 8 + j;
            bfr[j] = *(const bf16x8*)(Bf + ((size_t)(nt * 8 + kk) * 64 + lane) * 8);
        }
#pragma unroll
        for (int i = 0; i < 4; ++i)
#pragma unroll
            for (int j = 0; j < 8; ++j)
                acc[i][j] = __builtin_amdgcn_mfma_f32_16x16x32_bf16(
                    af[i], bfr[j], acc[i][j], 0, 0, 0);
    }

    float bv[8], gv[8], bev[8];
#pragma unroll
    for (int j = 0; j < 8; ++j) {
        const int n = wn * 128 + j * 16 + l16;
        bv[j] = bias[n]; gv[j] = gam[n]; bev[j] = bet[n];
    }

#pragma unroll
    for (int i = 0; i < 4; ++i) {
#pragma unroll
        for (int r = 0; r < 4; ++r) {
            const int rl  = wm * 64 + i * 16 + quad * 4 + r;
            const size_t row = (size_t)(bm + rl);
            float s1 = 0.f, s2 = 0.f;
#pragma unroll
            for (int j = 0; j < 8; ++j) {
                const int n = wn * 128 + j * 16 + l16;
                const float v = acc[i][j][r] + bv[j] + (float)Xres[row * 256 + n];
                acc[i][j][r] = v;
                s1 += v; s2 += v * v;
            }
#pragma unroll
            for (int off = 1; off < 16; off <<= 1) {
                s1 += __shfl_xor(s1, off, 64);
                s2 += __shfl_xor(s2, off, 64);
            }
            if (l16 == 0) red[rl][wn] = make_float2(s1, s2);
        }
    }
    __syncthreads();

#pragma unroll
    for (int i = 0; i < 4; ++i) {
#pragma unroll
        for (int r = 0; r < 4; ++r) {
            const int rl = wm * 64 + i * 16 + quad * 4 + r;
            const float2 p0 = red[rl][0], p1 = red[rl][1];
            const float mu  = (p0.x + p1.x) * (1.f / 256.f);
            const float ex2 = (p0.y + p1.y) * (1.f / 256.f);
            const float rstd = rsqrtf(fmaxf(ex2 - mu * mu, 0.f) + 1e-5f);
            const size_t row = (size_t)(bm + rl);
#pragma unroll
            for (int j = 0; j < 8; ++j) {
                const int n = wn * 128 + j * 16 + l16;
                Xout[row * 256 + n] = (bf16)((acc[i][j][r] - mu) * rstd * gv[j] + bev[j]);
            }
        }
    }
}

// --------------------------------------------------------------------------
// Fused FFN v6: Xout = LN(X + relu(X@W1^T+b1)@W2^T + b2)*gam + bet, in-place.
// 64-row tile, grid 1152, waves 2x2. 8 hidden chunks of 128.
// W1/W2 fragments direct from global (no weight LDS, no weight barriers).
// LDS: Xs 32KB + Ts 16KB (red aliases) = 48KB -> 3 blocks/CU.
// Barriers: 1 prologue + 2/hc (Ts transpose) = 17.
// --------------------------------------------------------------------------
__global__ __launch_bounds__(256, 2) void ffn_fused_k(
    const bf16* __restrict__ X,
    const bf16* __restrict__ W1f, const float* __restrict__ b1,
    const bf16* __restrict__ W2f, const float* __restrict__ b2,
    const float* __restrict__ gam, const float* __restrict__ bet,
    bf16* __restrict__ Xout)
{
    __shared__ __align__(16) char smem[49152];
    bf16* Xs = (bf16*)smem;                           // 64 x 256 (32 slots/row)
    bf16* Ts = (bf16*)(smem + 32768);                 // 64 x 128 (16 slots/row)
    float2 (*red)[2] = (float2 (*)[2])(void*)(smem + 32768);   // aliases Ts

    const int tid  = threadIdx.x;
    const int lane = tid & 63;
    const int wv   = tid >> 6;
    const int wm   = wv >> 1;
    const int wn   = wv & 1;
    const int quad = lane >> 4;
    const int l16  = lane & 15;
    const int bm   = blockIdx.x * 64;

    // stage Xs once
#pragma unroll
    for (int it = 0; it < 8; ++it) {
        const int L = it * 256 + tid;
        const int row = L >> 5, slot = L & 31;
        const int gch = (slot & 24) | ((slot ^ row) & 7);
        async_copy16(X + (size_t)(bm + row) * 256 + gch * 8,
                     (char*)Xs + (size_t)L * 16);
    }
    __syncthreads();

    f32x4 acc2[2][8] = {};

#pragma unroll 1
    for (int hc = 0; hc < 8; ++hc) {
        f32x4 accA[2][4] = {};

        // ---- phase A: accA = Xs @ W1c^T  (fragments from global, no barrier)
#pragma unroll
        for (int kk = 0; kk < 8; ++kk) {
            bf16x8 af[2], bfr[4];
            const int gc = kk * 4 + quad;
#pragma unroll
            for (int i = 0; i < 2; ++i) {
                const int m  = wm * 32 + i * 16 + l16;
                const int sl = (gc & 24) | ((gc ^ m) & 7);
                af[i] = *(const bf16x8*)((const char*)Xs + (m * 32 + sl) * 16);
            }
#pragma unroll
            for (int j = 0; j < 4; ++j) {
                const int nt = hc * 8 + wn * 4 + j;    // W1 n-tile (h/16)
                bfr[j] = *(const bf16x8*)(W1f + ((size_t)(nt * 8 + kk) * 64 + lane) * 8);
            }
#pragma unroll
            for (int i = 0; i < 2; ++i)
#pragma unroll
                for (int j = 0; j < 4; ++j)
                    accA[i][j] = __builtin_amdgcn_mfma_f32_16x16x32_bf16(
                        af[i], bfr[j], accA[i][j], 0, 0, 0);
        }

        __syncthreads();   // prev hc's Ts readers done

        // ---- Ts = relu(accA + b1)
#pragma unroll
        for (int j = 0; j < 4; ++j) {
            const int h  = wn * 64 + j * 16 + l16;
            const float bb = b1[hc * 128 + h];
            const int g  = h >> 3;
#pragma unroll
            for (int i = 0; i < 2; ++i)
#pragma unroll
                for (int r = 0; r < 4; ++r) {
                    const int m  = wm * 32 + i * 16 + quad * 4 + r;
                    const int sl = (g & 8) | ((g ^ m) & 7);
                    const float v = fmaxf(accA[i][j][r] + bb, 0.f);
                    *((bf16*)((char*)Ts + (m * 16 + sl) * 16 + (h & 7) * 2)) = (bf16)v;
                }
        }
        __syncthreads();

        // ---- phase B: acc2 += Ts @ W2c^T  (fragments from global, no barrier)
#pragma unroll
        for (int kc = 0; kc < 4; ++kc) {
            bf16x8 af[2], bfr[8];
            const int tc = kc * 4 + quad;
#pragma unroll
            for (int i = 0; i < 2; ++i) {
                const int m  = wm * 32 + i * 16 + l16;
                const int sl = (tc & 8) | ((tc ^ m) & 7);
                af[i] = *(const bf16x8*)((const char*)Ts + (m * 16 + sl) * 16);
            }
            const int kcg = hc * 4 + kc;               // W2 k-chunk (of 32)
#pragma unroll
            for (int j = 0; j < 8; ++j) {
                const int nt = wn * 8 + j;             // W2 n-tile
                bfr[j] = *(const bf16x8*)(W2f + ((size_t)(nt * 32 + kcg) * 64 + lane) * 8);
            }
#pragma unroll
            for (int i = 0; i < 2; ++i)
#pragma unroll
                for (int j = 0; j < 8; ++j)
                    acc2[i][j] = __builtin_amdgcn_mfma_f32_16x16x32_bf16(
                        af[i], bfr[j], acc2[i][j], 0, 0, 0);
        }
    }

    __syncthreads();   // last Ts reads before red[] aliases it

    // ---- epilogue: bias + residual (from Xs) + LayerNorm
    float bv[8], gv[8], bev[8];
#pragma unroll
    for (int j = 0; j < 8; ++j) {
        const int n = wn * 128 + j * 16 + l16;
        bv[j] = b2[n]; gv[j] = gam[n]; bev[j] = bet[n];
    }

#pragma unroll
    for (int i = 0; i < 2; ++i) {
#pragma unroll
        for (int r = 0; r < 4; ++r) {
            const int rl = wm * 32 + i * 16 + quad * 4 + r;
            float s1 = 0.f, s2 = 0.f;
#pragma unroll
            for (int j = 0; j < 8; ++j) {
                const int n  = wn * 128 + j * 16 + l16;
                const int gc = n >> 3;
                const int sl = (gc & 24) | ((gc ^ rl) & 7);
                const float xr = (float)*((const bf16*)((const char*)Xs +
                                   (rl * 32 + sl) * 16 + (n & 7) * 2));
                const float v = acc2[i][j][r] + bv[j] + xr;
                acc2[i][j][r] = v;
                s1 += v; s2 += v * v;
            }
#pragma unroll
            for (int off = 1; off < 16; off <<= 1) {
                s1 += __shfl_xor(s1, off, 64);
                s2 += __shfl_xor(s2, off, 64);
            }
            if (l16 == 0) red[rl][wn] = make_float2(s1, s2);
        }
    }
    __syncthreads();

#pragma unroll
    for (int i = 0; i < 2; ++i) {
#pragma unroll
        for (int r = 0; r < 4; ++r) {
            const int rl = wm * 32 + i * 16 + quad * 4 + r;
            const float2 p0 = red[rl][0], p1 = red[rl][1];
            const float mu  = (p0.x + p1.x) * (1.f / 256.f);
            const float ex2 = (p0.y + p1.y) * (1.f / 256.f);
            const float rstd = rsqrtf(fmaxf(ex2 - mu * mu, 0.f) + 1e-5f);
            const size_t row = (size_t)(bm + rl);
#pragma unroll
            for (int j = 0; j < 8; ++j) {
                const int n = wn * 128 + j * 16 + l16;
                Xout[row * 256 + n] = (bf16)((acc2[i][j][r] - mu) * rstd * gv[j] + bev[j]);
            }
        }
    }
}

// --------------------------------------------------------------------------
// attention v2: per sequence (4 tokens), 8 heads x dh=32, softmax over 4.
// --------------------------------------------------------------------------
__global__ __launch_bounds__(256) void attention_k(const bf16* __restrict__ QKV,
                                                   bf16* __restrict__ SA)
{
    __shared__ float qf[4][4][768];
    __shared__ float sc[4][8][4][4];

    const int tid  = threadIdx.x;
    const int wv   = tid >> 6;
    const int lane = tid & 63;
    const int s    = blockIdx.x * 4 + wv;

    const bf16* base = QKV + (size_t)s * 4 * 768;
#pragma unroll
    for (int it = 0; it < 6; ++it) {
        const int idx = it * 64 + lane;
        const bf16x8 v = *(const bf16x8*)(base + idx * 8);
        const int tok = idx / 96;
        const int e   = (idx % 96) * 8;
        f32x4 f0, f1;
#pragma unroll
        for (int i = 0; i < 4; ++i) { f0[i] = (float)v[i]; f1[i] = (float)v[4 + i]; }
        *(f32x4*)(&qf[wv][tok][e])     = f0;
        *(f32x4*)(&qf[wv][tok][e + 4]) = f1;
    }
    __syncthreads();

#pragma unroll
    for (int rep = 0; rep < 2; ++rep) {
        const int t = rep * 64 + lane;
        const int h = t >> 4, i = (t >> 2) & 3, j = t & 3;
        const float* q = &qf[wv][i][h * 32];
        const float* k = &qf[wv][j][256 + h * 32];
        float a = 0.f;
#pragma unroll
        for (int dd = 0; dd < 32; ++dd) {
            const int d = (dd + lane) & 31;
            a += q[d] * k[d];
        }
        sc[wv][h][i][j] = a * 0.17677669529663687f;
    }
    __syncthreads();

    if (lane < 32) {
        const int h = lane >> 2, i = lane & 3;
        float s0 = sc[wv][h][i][0], s1 = sc[wv][h][i][1];
        float s2 = sc[wv][h][i][2], s3 = sc[wv][h][i][3];
        float m = fmaxf(fmaxf(s0, s1), fmaxf(s2, s3));
        float e0 = expf(s0 - m), e1 = expf(s1 - m);
        float e2 = expf(s2 - m), e3 = expf(s3 - m);
        float inv = 1.f / (e0 + e1 + e2 + e3);
        sc[wv][h][i][0] = e0 * inv;
        sc[wv][h][i][1] = e1 * inv;
        sc[wv][h][i][2] = e2 * inv;
        sc[wv][h][i][3] = e3 * inv;
    }
    __syncthreads();

    const int h = lane >> 3;
#pragma unroll
    for (int i = 0; i < 4; ++i) {
        f32x4 a = {0.f, 0.f, 0.f, 0.f};
#pragma unroll
        for (int j = 0; j < 4; ++j) {
            const float p = sc[wv][h][i][j];
            const f32x4 v = *(const f32x4*)(&qf[wv][j][512 + lane * 4]);
#pragma unroll
            for (int q = 0; q < 4; ++q) a[q] += p * v[q];
        }
        bf16x4 o;
#pragma unroll
        for (int q = 0; q < 4; ++q) o[q] = (bf16)a[q];
        *(bf16x4*)(SA + (size_t)(s * 4 + i) * 256 + lane * 4) = o;
    }
}

// --------------------------------------------------------------------------
// out[b][c][hw] = sum_e (mean_cam X[p*4+cam][e]) * Wout[c][e] + bout[c]
// --------------------------------------------------------------------------
__global__ __launch_bounds__(256) void out_proj_k(const bf16* __restrict__ X,
                                                  const float* __restrict__ Wout,
                                                  const float* __restrict__ bout,
                                                  float* __restrict__ out)
{
    __shared__ float fused[16][260];
    const int tid = threadIdx.x;
    const int p0  = blockIdx.x * 16;

#pragma unroll
    for (int it = 0; it < 16; ++it) {
        const int idx = it * 256 + tid;
        const int pix = idx >> 8, e = idx & 255;
        const size_t base = (size_t)(p0 + pix) * 1024 + e;
        const float s = (float)X[base] + (float)X[base + 256] +
                        (float)X[base + 512] + (float)X[base + 768];
        fused[pix][e] = s * 0.25f;
    }
    __syncthreads();

    const int pix = tid & 15;
    const int c0  = tid >> 4;
    const int p   = p0 + pix;
    const int b   = p / 9216;
    const int hw  = p % 9216;
#pragma unroll
    for (int it = 0; it < 4; ++it) {
        const int c = it * 16 + c0;
        const float* w = Wout + c * 256;
        float acc = bout[c];
#pragma unroll 8
        for (int e = 0; e < 256; ++e) acc += fused[pix][e] * w[e];
        out[((size_t)b * 64 + c) * 9216 + hw] = acc;
    }
}

// --------------------------------------------------------------------------
extern "C" void kernel_launch(void* const* d_in, const int* in_sizes, int n_in,
                              void* d_out, int out_size, void* d_ws, size_t ws_size,
                              hipStream_t stream)
{
    const float* features = (const float*)d_in[0];
    const float* Wp   = (const float*)d_in[1];
    const float* bp   = (const float*)d_in[2];
    const float* Wqkv = (const float*)d_in[3];
    const float* bqkv = (const float*)d_in[4];
    const float* Wo   = (const float*)d_in[5];
    const float* bo   = (const float*)d_in[6];
    const float* W1   = (const float*)d_in[7];
    const float* b1   = (const float*)d_in[8];
    const float* W2   = (const float*)d_in[9];
    const float* b2   = (const float*)d_in[10];
    const float* g1   = (const float*)d_in[11];
    const float* be1  = (const float*)d_in[12];
    const float* g2   = (const float*)d_in[13];
    const float* be2  = (const float*)d_in[14];
    const float* Wout = (const float*)d_in[15];
    const float* bout = (const float*)d_in[16];
    float* out = (float*)d_out;

    char* ws = (char*)d_ws;
    bf16* X   = (bf16*)(ws);                    // 73728*256
    bf16* QKV = (bf16*)(ws + 37748736ull);      // 73728*768
    bf16* SAb = (bf16*)(ws + 150994944ull);     // 73728*256
    bf16* Xf  = (bf16*)(ws + 188743680ull);     // 73728*64
    bf16* WpF = (bf16*)(ws + 198180864ull);     // 256*64 fragments
    bf16* Wfr = (bf16*)(ws + 226492416ull);     // fragment-packed weights

    bf16* WqkvF = Wfr;                 // 2 x 768*256
    bf16* WoF   = Wfr + 393216;        // 2 x 256*256
    bf16* W1F   = Wfr + 524288;        // 2 x 1024*256
    bf16* W2F   = Wfr + 1048576;       // 2 x 256*1024

    pack_frag_k<<<776, 256, 0, stream>>>(Wp, Wqkv, Wo, W1, W2,
                                         WpF, WqkvF, WoF, W1F, W2F);

    feat_pack_k<<<dim3(144, 8), 256, 0, stream>>>(features, Xf);
    gemm_a<64, false><<<dim3(2, 576), 256, 0, stream>>>(Xf, WpF, bp, X, 256);

    for (int l = 0; l < 2; ++l) {
        gemm_a<256, false><<<dim3(6, 576), 256, 0, stream>>>(
            X, WqkvF + l * 196608, bqkv + l * 768, QKV, 768);
        attention_k<<<4608, 256, 0, stream>>>(QKV, SAb);
        gemm_ln_a<<<576, 256, 0, stream>>>(
            SAb, WoF + l * 65536, bo + l * 256, X,
            g1 + l * 256, be1 + l * 256, X);
        ffn_fused_k<<<1152, 256, 0, stream>>>(
            X, W1F + l * 262144, b1 + l * 1024,
            W2F + l * 262144, b2 + l * 256,
            g2 + l * 256, be2 + l * 256, X);
    }

    out_proj_k<<<1152, 256, 0, stream>>>(X, Wout, bout, out);
}

// Round 11
// 661.809 us; speedup vs baseline: 1.9293x; 1.2806x over previous
//
#include <hip/hip_runtime.h>
#include <cstdint>
#include <cstddef>

// ---------------------------------------------------------------------------
// TransformerMultiViewFusion (MI355X / gfx950), round 11.
//
//  R11 = R7 (best, 648us) + one surgical ffn change:
//   phase A keeps R7's LDS-staged W1 quarters (proven, bounded reg pressure);
//   phase B consumes W2 as MFMA fragments DIRECT from global (R10 layout,
//   numerically verified), kc-loop unroll 2 to cap operand regs (~72 VGPR
//   transient). Barrier-steps per block: 72 -> 33. R10's mistake (both
//   phases fragment-direct, 32 hoisted loads -> 29MB scratch) avoided.
//  Tripwire: ffn WRITE_SIZE > 45MB => spill => revert phase B.
//
//  Workspace: X@0 | QKV@37748736 | SA@150994944 | Xf@188743680 |
//             WpB@198180864 | W2F@198213632 | Wb@226492416
// ---------------------------------------------------------------------------

typedef __bf16 bf16;
typedef __bf16 bf16x8 __attribute__((ext_vector_type(8)));
typedef __bf16 bf16x4 __attribute__((ext_vector_type(4)));
typedef float  f32x4  __attribute__((ext_vector_type(4)));

__device__ __forceinline__ void async_copy16(const void* g, void* l)
{
    __builtin_amdgcn_global_load_lds(
        (__attribute__((address_space(1))) void*)g,
        (__attribute__((address_space(3))) void*)l,
        16, 0, 0);
}

// --------------------------------------------------------------------------
// all 5 weight packs in one launch. 1589248 = 6208*256 exactly.
// (row-major bf16; W2 row-major is unused now but harmless to pack)
// --------------------------------------------------------------------------
__global__ void pack_all_k(const float* __restrict__ s0, const float* __restrict__ s1,
                           const float* __restrict__ s2, const float* __restrict__ s3,
                           const float* __restrict__ s4,
                           bf16* __restrict__ d0, bf16* __restrict__ d1,
                           bf16* __restrict__ d2, bf16* __restrict__ d3,
                           bf16* __restrict__ d4)
{
    const int i = blockIdx.x * 256 + threadIdx.x;
    if (i < 393216)       d0[i] = (bf16)s0[i];
    else if (i < 524288)  d1[i - 393216] = (bf16)s1[i - 393216];
    else if (i < 1048576) d2[i - 524288] = (bf16)s2[i - 524288];
    else if (i < 1572864) d3[i - 1048576] = (bf16)s3[i - 1048576];
    else                  d4[i - 1572864] = (bf16)s4[i - 1572864];
}

// --------------------------------------------------------------------------
// W2 -> MFMA-fragment layout (bf16). Entry e=(nt*32+kc)*64+lane holds
// W2[nt*16+(lane&15)][kc*32+(lane>>4)*8 .. +8].  2 layers x 32768 entries.
// --------------------------------------------------------------------------
__global__ void pack_w2f_k(const float* __restrict__ W2, bf16* __restrict__ W2F)
{
    const int g  = blockIdx.x * 256 + threadIdx.x;   // 0..65535
    const int l  = g >> 15;
    const int e  = g & 32767;
    const int nt   = e >> 11;            // / 2048
    const int rem  = e & 2047;
    const int kc   = rem >> 6;
    const int lane = rem & 63;
    const int row  = nt * 16 + (lane & 15);
    const int col  = kc * 32 + (lane >> 4) * 8;
    const float* src = W2 + (size_t)l * 262144;
    bf16x8 v;
#pragma unroll
    for (int q = 0; q < 8; ++q) v[q] = (bf16)src[(size_t)row * 1024 + col + q];
    *(bf16x8*)(W2F + (size_t)l * 262144 + (size_t)e * 8) = v;
}

// --------------------------------------------------------------------------
// feat transpose-pack: Xf[t][c] = (bf16)feat[cam][b][c][hw]
// --------------------------------------------------------------------------
__global__ __launch_bounds__(256) void feat_pack_k(const float* __restrict__ feat,
                                                   bf16* __restrict__ Xf)
{
    __shared__ float ft[64][68];

    const int tid  = threadIdx.x;
    const int camb = blockIdx.y;
    const int cam  = camb >> 1;
    const int b    = camb & 1;
    const int hw0  = blockIdx.x * 64;

    const float* fb = feat + (size_t)camb * 64 * 9216 + hw0;
#pragma unroll
    for (int rep = 0; rep < 16; ++rep) {
        const int idx = rep * 256 + tid;
        const int c = idx >> 6, p = idx & 63;
        ft[p][c] = fb[(size_t)c * 9216 + p];
    }
    __syncthreads();

    const int pbase = b * 9216 + hw0;
#pragma unroll
    for (int rep = 0; rep < 2; ++rep) {
        const int idx = rep * 256 + tid;
        const int p = idx >> 3, cc = idx & 7;
        const f32x4 a = *(const f32x4*)(&ft[p][cc * 8]);
        const f32x4 c4 = *(const f32x4*)(&ft[p][cc * 8 + 4]);
        bf16x8 v;
#pragma unroll
        for (int i = 0; i < 4; ++i) { v[i] = (bf16)a[i]; v[4 + i] = (bf16)c4[i]; }
        const size_t t = (size_t)(pbase + p) * 4 + cam;
        *(bf16x8*)(Xf + t * 64 + cc * 8) = v;
    }
}

// --------------------------------------------------------------------------
// GEMM-BT: C[M,N] = A[M,K] @ B[N,K]^T + bias[N], bf16 in/out. 128x128 tile.
// --------------------------------------------------------------------------
template <bool RELU>
__global__ __launch_bounds__(256, 2) void gemm_bt(
    const bf16* __restrict__ A, const bf16* __restrict__ B,
    const float* __restrict__ bias, bf16* __restrict__ C,
    int N, int K)
{
    __shared__ __align__(16) bf16 As[128 * 64];
    __shared__ __align__(16) bf16 Bs[128 * 64];

    const int tid  = threadIdx.x;
    const int lane = tid & 63;
    const int wv   = tid >> 6;
    const int wm   = wv >> 1;
    const int wn   = wv & 1;
    const int bm   = blockIdx.y * 128;
    const int bn   = blockIdx.x * 128;

    const int r8  = lane >> 3;
    const int p8  = lane & 7;
    const int gch = p8 ^ r8;

    const int quad = lane >> 4;
    const int l16  = lane & 15;

    f32x4 acc[4][4] = {};

    for (int k0 = 0; k0 < K; k0 += 64) {
#pragma unroll
        for (int inst = 0; inst < 4; ++inst) {
            const int row = wv * 32 + inst * 8 + r8;
            const bf16* ga = A + (size_t)(bm + row) * K + (k0 + gch * 8);
            const bf16* gb = B + (size_t)(bn + row) * K + (k0 + gch * 8);
            async_copy16(ga, (char*)As + (wv * 4 + inst) * 1024);
            async_copy16(gb, (char*)Bs + (wv * 4 + inst) * 1024);
        }
        __syncthreads();

#pragma unroll
        for (int kk = 0; kk < 2; ++kk) {
            bf16x8 af[4], bfr[4];
            const int lch = kk * 4 + quad;
#pragma unroll
            for (int i = 0; i < 4; ++i) {
                const int m = wm * 64 + i * 16 + l16;
                af[i] = *(const bf16x8*)((const char*)As + (m * 8 + (lch ^ (m & 7))) * 16);
                const int n = wn * 64 + i * 16 + l16;
                bfr[i] = *(const bf16x8*)((const char*)Bs + (n * 8 + (lch ^ (n & 7))) * 16);
            }
#pragma unroll
            for (int i = 0; i < 4; ++i)
#pragma unroll
                for (int j = 0; j < 4; ++j)
                    acc[i][j] = __builtin_amdgcn_mfma_f32_16x16x32_bf16(
                        af[i], bfr[j], acc[i][j], 0, 0, 0);
        }
        __syncthreads();
    }

#pragma unroll
    for (int j = 0; j < 4; ++j) {
        const int n = bn + wn * 64 + j * 16 + l16;
        const float bv = bias[n];
#pragma unroll
        for (int i = 0; i < 4; ++i) {
            const int mb = bm + wm * 64 + i * 16 + quad * 4;
#pragma unroll
            for (int r = 0; r < 4; ++r) {
                float v = acc[i][j][r] + bv;
                if (RELU) v = fmaxf(v, 0.f);
                C[(size_t)(mb + r) * N + n] = (bf16)v;
            }
        }
    }
}

// --------------------------------------------------------------------------
// GEMM-BT + bias + residual + LayerNorm (Wo path, K=256). 128x256 tile.
// --------------------------------------------------------------------------
__global__ __launch_bounds__(256, 2) void gemm_ln_k(
    const bf16* __restrict__ A, const bf16* __restrict__ B,
    const float* __restrict__ bias, const bf16* __restrict__ Xres,
    const float* __restrict__ gam, const float* __restrict__ bet,
    bf16* __restrict__ Xout, int K)
{
    __shared__ __align__(16) bf16 S[24576];
    __shared__ float2 red[128][2];

    const int tid  = threadIdx.x;
    const int lane = tid & 63;
    const int wv   = tid >> 6;
    const int wm   = wv >> 1;
    const int wn   = wv & 1;
    const int bm   = blockIdx.x * 128;
    const int quad = lane >> 4;
    const int l16  = lane & 15;

    f32x4 acc[4][8] = {};

    for (int k0 = 0; k0 < K; k0 += 64) {
#pragma unroll
        for (int s = 0; s < 12; ++s) {
            const int L   = s * 256 + tid;
            const int row = L >> 3;
            const int gch = (L & 7) ^ (row & 7);
            const bf16* g = (row < 128)
                ? A + (size_t)(bm + row) * K + (k0 + gch * 8)
                : B + (size_t)(row - 128) * K + (k0 + gch * 8);
            async_copy16(g, (char*)S + (size_t)L * 16);
        }
        __syncthreads();

#pragma unroll
        for (int kk = 0; kk < 2; ++kk) {
            const int lch = kk * 4 + quad;
            bf16x8 af[4], bfr[8];
#pragma unroll
            for (int i = 0; i < 4; ++i) {
                const int m = wm * 64 + i * 16 + l16;
                af[i] = *(const bf16x8*)((const char*)S + (m * 8 + (lch ^ (m & 7))) * 16);
            }
#pragma unroll
            for (int j = 0; j < 8; ++j) {
                const int n = wn * 128 + j * 16 + l16;
                bfr[j] = *(const bf16x8*)((const char*)S + ((128 + n) * 8 + (lch ^ (n & 7))) * 16);
            }
#pragma unroll
            for (int i = 0; i < 4; ++i)
#pragma unroll
                for (int j = 0; j < 8; ++j)
                    acc[i][j] = __builtin_amdgcn_mfma_f32_16x16x32_bf16(
                        af[i], bfr[j], acc[i][j], 0, 0, 0);
        }
        __syncthreads();
    }

    float bv[8], gv[8], bev[8];
#pragma unroll
    for (int j = 0; j < 8; ++j) {
        const int n = wn * 128 + j * 16 + l16;
        bv[j] = bias[n]; gv[j] = gam[n]; bev[j] = bet[n];
    }

#pragma unroll
    for (int i = 0; i < 4; ++i) {
#pragma unroll
        for (int r = 0; r < 4; ++r) {
            const int rl  = wm * 64 + i * 16 + quad * 4 + r;
            const size_t row = (size_t)(bm + rl);
            float s1 = 0.f, s2 = 0.f;
#pragma unroll
            for (int j = 0; j < 8; ++j) {
                const int n = wn * 128 + j * 16 + l16;
                const float v = acc[i][j][r] + bv[j] + (float)Xres[row * 256 + n];
                acc[i][j][r] = v;
                s1 += v; s2 += v * v;
            }
#pragma unroll
            for (int off = 1; off < 16; off <<= 1) {
                s1 += __shfl_xor(s1, off, 64);
                s2 += __shfl_xor(s2, off, 64);
            }
            if (l16 == 0) red[rl][wn] = make_float2(s1, s2);
        }
    }
    __syncthreads();

#pragma unroll
    for (int i = 0; i < 4; ++i) {
#pragma unroll
        for (int r = 0; r < 4; ++r) {
            const int rl = wm * 64 + i * 16 + quad * 4 + r;
            const float2 p0 = red[rl][0], p1 = red[rl][1];
            const float mu  = (p0.x + p1.x) * (1.f / 256.f);
            const float ex2 = (p0.y + p1.y) * (1.f / 256.f);
            const float rstd = rsqrtf(fmaxf(ex2 - mu * mu, 0.f) + 1e-5f);
            const size_t row = (size_t)(bm + rl);
#pragma unroll
            for (int j = 0; j < 8; ++j) {
                const int n = wn * 128 + j * 16 + l16;
                Xout[row * 256 + n] = (bf16)((acc[i][j][r] - mu) * rstd * gv[j] + bev[j]);
            }
        }
    }
}

// --------------------------------------------------------------------------
// W1 quarter stage, step st (0..31): hc = st>>2, q = st&3.
// [128 h][64 k], slot = c ^ (row&7). 16KB into stg[st&1].
// --------------------------------------------------------------------------
__device__ __forceinline__ void ffn_stage_w1(int st, const bf16* __restrict__ W1,
                                             char* stg, int tid)
{
    char* buf = stg + (size_t)(st & 1) * 16384;
    const int hc = st >> 2;
    const int q  = st & 3;
#pragma unroll
    for (int it = 0; it < 4; ++it) {
        const int L = it * 256 + tid;
        const int row = L >> 3, psl = L & 7;
        const int c = psl ^ (row & 7);
        async_copy16(W1 + (size_t)(hc * 128 + row) * 256 + q * 64 + c * 8,
                     buf + (size_t)L * 16);
    }
}

// --------------------------------------------------------------------------
// Fused FFN v5: Xout = LN(X + relu(X@W1^T+b1)@W2^T + b2)*gam + bet, in-place.
// 64-row tile, grid 1152, 4 waves 2x2. 8 hidden chunks of 128.
// Phase A: R7's staged W1 quarters (ping-pong 16KB, 4 barriers/hc).
// Phase B: W2 fragments DIRECT from global (R10 layout), unroll 2, 0 barriers.
// LDS: Xs 32K | Ts 16K (red aliases) | stage 2x16K = 80KB -> 2 blocks/CU.
// --------------------------------------------------------------------------
__global__ __launch_bounds__(256, 2) void ffn_fused_k(
    const bf16* __restrict__ X,
    const bf16* __restrict__ W1, const float* __restrict__ b1,
    const bf16* __restrict__ W2f, const float* __restrict__ b2,
    const float* __restrict__ gam, const float* __restrict__ bet,
    bf16* __restrict__ Xout)
{
    __shared__ __align__(16) char smem[81920];
    bf16* Xs = (bf16*)smem;                       // 64 x 256 (32 slots/row)
    bf16* Ts = (bf16*)(smem + 32768);             // 64 x 128 (16 slots/row)
    float2 (*red)[2] = (float2 (*)[2])(void*)(smem + 32768);   // aliases Ts
    char* stg = smem + 49152;                     // 2 x 16KB

    const int tid  = threadIdx.x;
    const int lane = tid & 63;
    const int wv   = tid >> 6;
    const int wm   = wv >> 1;
    const int wn   = wv & 1;
    const int quad = lane >> 4;
    const int l16  = lane & 15;
    const int bm   = blockIdx.x * 64;

    // prologue: Xs (2048 x 16B) + first W1 quarter
#pragma unroll
    for (int it = 0; it < 8; ++it) {
        const int L = it * 256 + tid;
        const int row = L >> 5, slot = L & 31;
        const int gch = (slot & 24) | ((slot ^ row) & 7);
        async_copy16(X + (size_t)(bm + row) * 256 + gch * 8,
                     (char*)Xs + (size_t)L * 16);
    }
    ffn_stage_w1(0, W1, stg, tid);
    __syncthreads();

    f32x4 acc2[2][8] = {};

#pragma unroll 1
    for (int hc = 0; hc < 8; ++hc) {
        f32x4 accA[2][4] = {};

        // ---- phase A: accA = Xs @ W1c^T, 4 staged steps of 64k
#pragma unroll
        for (int q = 0; q < 4; ++q) {
            const int st = hc * 4 + q;
            if (st + 1 < 32) ffn_stage_w1(st + 1, W1, stg, tid);
            const char* cur = stg + (size_t)(st & 1) * 16384;
#pragma unroll
            for (int kk = 0; kk < 2; ++kk) {
                const int ch = kk * 4 + quad;          // buffer chunk 0..7
                const int gc = q * 8 + ch;             // Xs chunk 0..31
                bf16x8 af[2], bfr[4];
#pragma unroll
                for (int i = 0; i < 2; ++i) {
                    const int m  = wm * 32 + i * 16 + l16;
                    const int sl = (gc & 24) | ((gc ^ m) & 7);
                    af[i] = *(const bf16x8*)((const char*)Xs + (m * 32 + sl) * 16);
                }
#pragma unroll
                for (int j = 0; j < 4; ++j) {
                    const int n  = wn * 64 + j * 16 + l16;
                    const int sl = ch ^ (n & 7);
                    bfr[j] = *(const bf16x8*)(cur + (n * 8 + sl) * 16);
                }
#pragma unroll
                for (int i = 0; i < 2; ++i)
#pragma unroll
                    for (int j = 0; j < 4; ++j)
                        accA[i][j] = __builtin_amdgcn_mfma_f32_16x16x32_bf16(
                            af[i], bfr[j], accA[i][j], 0, 0, 0);
            }
            if (q == 3) {
                // Ts = relu(accA + b1)  (prev hc's phase-B reads are done:
                // barriers at q=0..2 of this hc separate them from this write)
#pragma unroll
                for (int j = 0; j < 4; ++j) {
                    const int h  = wn * 64 + j * 16 + l16;
                    const float bb = b1[hc * 128 + h];
                    const int g  = h >> 3;
#pragma unroll
                    for (int i = 0; i < 2; ++i)
#pragma unroll
                        for (int r = 0; r < 4; ++r) {
                            const int m  = wm * 32 + i * 16 + quad * 4 + r;
                            const int sl = (g & 8) | ((g ^ m) & 7);
                            const float v = fmaxf(accA[i][j][r] + bb, 0.f);
                            *((bf16*)((char*)Ts + (m * 16 + sl) * 16 + (h & 7) * 2)) = (bf16)v;
                        }
                }
            }
            __syncthreads();
        }

        // ---- phase B: acc2 += Ts @ W2c^T, W2 fragments from global. No barriers.
#pragma unroll 2
        for (int kc = 0; kc < 4; ++kc) {
            const int tc = kc * 4 + quad;              // Ts chunk 0..15
            bf16x8 af[2], bfr[8];
#pragma unroll
            for (int i = 0; i < 2; ++i) {
                const int m  = wm * 32 + i * 16 + l16;
                const int sl = (tc & 8) | ((tc ^ m) & 7);
                af[i] = *(const bf16x8*)((const char*)Ts + (m * 16 + sl) * 16);
            }
            const int kcg = hc * 4 + kc;               // W2 k-chunk (0..31)
#pragma unroll
            for (int j = 0; j < 8; ++j) {
                const int nt = wn * 8 + j;             // W2 n-tile
                bfr[j] = *(const bf16x8*)(W2f + ((size_t)(nt * 32 + kcg) * 64 + lane) * 8);
            }
#pragma unroll
            for (int i = 0; i < 2; ++i)
#pragma unroll
                for (int j = 0; j < 8; ++j)
                    acc2[i][j] = __builtin_amdgcn_mfma_f32_16x16x32_bf16(
                        af[i], bfr[j], acc2[i][j], 0, 0, 0);
        }
    }

    __syncthreads();   // last phase-B Ts reads done before red[] aliases it

    // ---- epilogue: bias + residual (from Xs) + LayerNorm
    float bv[8], gv[8], bev[8];
#pragma unroll
    for (int j = 0; j < 8; ++j) {
        const int n = wn * 128 + j * 16 + l16;
        bv[j] = b2[n]; gv[j] = gam[n]; bev[j] = bet[n];
    }

#pragma unroll
    for (int i = 0; i < 2; ++i) {
#pragma unroll
        for (int r = 0; r < 4; ++r) {
            const int rl = wm * 32 + i * 16 + quad * 4 + r;
            float s1 = 0.f, s2 = 0.f;
#pragma unroll
            for (int j = 0; j < 8; ++j) {
                const int n  = wn * 128 + j * 16 + l16;
                const int gc = n >> 3;
                const int sl = (gc & 24) | ((gc ^ rl) & 7);
                const float xr = (float)*((const bf16*)((const char*)Xs +
                                   (rl * 32 + sl) * 16 + (n & 7) * 2));
                const float v = acc2[i][j][r] + bv[j] + xr;
                acc2[i][j][r] = v;
                s1 += v; s2 += v * v;
            }
#pragma unroll
            for (int off = 1; off < 16; off <<= 1) {
                s1 += __shfl_xor(s1, off, 64);
                s2 += __shfl_xor(s2, off, 64);
            }
            if (l16 == 0) red[rl][wn] = make_float2(s1, s2);
        }
    }
    __syncthreads();

#pragma unroll
    for (int i = 0; i < 2; ++i) {
#pragma unroll
        for (int r = 0; r < 4; ++r) {
            const int rl = wm * 32 + i * 16 + quad * 4 + r;
            const float2 p0 = red[rl][0], p1 = red[rl][1];
            const float mu  = (p0.x + p1.x) * (1.f / 256.f);
            const float ex2 = (p0.y + p1.y) * (1.f / 256.f);
            const float rstd = rsqrtf(fmaxf(ex2 - mu * mu, 0.f) + 1e-5f);
            const size_t row = (size_t)(bm + rl);
#pragma unroll
            for (int j = 0; j < 8; ++j) {
                const int n = wn * 128 + j * 16 + l16;
                Xout[row * 256 + n] = (bf16)((acc2[i][j][r] - mu) * rstd * gv[j] + bev[j]);
            }
        }
    }
}

// --------------------------------------------------------------------------
// attention v2: per sequence (4 tokens), 8 heads x dh=32, softmax over 4.
// --------------------------------------------------------------------------
__global__ __launch_bounds__(256) void attention_k(const bf16* __restrict__ QKV,
                                                   bf16* __restrict__ SA)
{
    __shared__ float qf[4][4][768];
    __shared__ float sc[4][8][4][4];

    const int tid  = threadIdx.x;
    const int wv   = tid >> 6;
    const int lane = tid & 63;
    const int s    = blockIdx.x * 4 + wv;

    const bf16* base = QKV + (size_t)s * 4 * 768;
#pragma unroll
    for (int it = 0; it < 6; ++it) {
        const int idx = it * 64 + lane;
        const bf16x8 v = *(const bf16x8*)(base + idx * 8);
        const int tok = idx / 96;
        const int e   = (idx % 96) * 8;
        f32x4 f0, f1;
#pragma unroll
        for (int i = 0; i < 4; ++i) { f0[i] = (float)v[i]; f1[i] = (float)v[4 + i]; }
        *(f32x4*)(&qf[wv][tok][e])     = f0;
        *(f32x4*)(&qf[wv][tok][e + 4]) = f1;
    }
    __syncthreads();

#pragma unroll
    for (int rep = 0; rep < 2; ++rep) {
        const int t = rep * 64 + lane;
        const int h = t >> 4, i = (t >> 2) & 3, j = t & 3;
        const float* q = &qf[wv][i][h * 32];
        const float* k = &qf[wv][j][256 + h * 32];
        float a = 0.f;
#pragma unroll
        for (int dd = 0; dd < 32; ++dd) {
            const int d = (dd + lane) & 31;
            a += q[d] * k[d];
        }
        sc[wv][h][i][j] = a * 0.17677669529663687f;
    }
    __syncthreads();

    if (lane < 32) {
        const int h = lane >> 2, i = lane & 3;
        float s0 = sc[wv][h][i][0], s1 = sc[wv][h][i][1];
        float s2 = sc[wv][h][i][2], s3 = sc[wv][h][i][3];
        float m = fmaxf(fmaxf(s0, s1), fmaxf(s2, s3));
        float e0 = expf(s0 - m), e1 = expf(s1 - m);
        float e2 = expf(s2 - m), e3 = expf(s3 - m);
        float inv = 1.f / (e0 + e1 + e2 + e3);
        sc[wv][h][i][0] = e0 * inv;
        sc[wv][h][i][1] = e1 * inv;
        sc[wv][h][i][2] = e2 * inv;
        sc[wv][h][i][3] = e3 * inv;
    }
    __syncthreads();

    const int h = lane >> 3;
#pragma unroll
    for (int i = 0; i < 4; ++i) {
        f32x4 a = {0.f, 0.f, 0.f, 0.f};
#pragma unroll
        for (int j = 0; j < 4; ++j) {
            const float p = sc[wv][h][i][j];
            const f32x4 v = *(const f32x4*)(&qf[wv][j][512 + lane * 4]);
#pragma unroll
            for (int q = 0; q < 4; ++q) a[q] += p * v[q];
        }
        bf16x4 o;
#pragma unroll
        for (int q = 0; q < 4; ++q) o[q] = (bf16)a[q];
        *(bf16x4*)(SA + (size_t)(s * 4 + i) * 256 + lane * 4) = o;
    }
}

// --------------------------------------------------------------------------
// out[b][c][hw] = sum_e (mean_cam X[p*4+cam][e]) * Wout[c][e] + bout[c]
// --------------------------------------------------------------------------
__global__ __launch_bounds__(256) void out_proj_k(const bf16* __restrict__ X,
                                                  const float* __restrict__ Wout,
                                                  const float* __restrict__ bout,
                                                  float* __restrict__ out)
{
    __shared__ float fused[16][260];
    const int tid = threadIdx.x;
    const int p0  = blockIdx.x * 16;

#pragma unroll
    for (int it = 0; it < 16; ++it) {
        const int idx = it * 256 + tid;
        const int pix = idx >> 8, e = idx & 255;
        const size_t base = (size_t)(p0 + pix) * 1024 + e;
        const float s = (float)X[base] + (float)X[base + 256] +
                        (float)X[base + 512] + (float)X[base + 768];
        fused[pix][e] = s * 0.25f;
    }
    __syncthreads();

    const int pix = tid & 15;
    const int c0  = tid >> 4;
    const int p   = p0 + pix;
    const int b   = p / 9216;
    const int hw  = p % 9216;
#pragma unroll
    for (int it = 0; it < 4; ++it) {
        const int c = it * 16 + c0;
        const float* w = Wout + c * 256;
        float acc = bout[c];
#pragma unroll 8
        for (int e = 0; e < 256; ++e) acc += fused[pix][e] * w[e];
        out[((size_t)b * 64 + c) * 9216 + hw] = acc;
    }
}

// --------------------------------------------------------------------------
extern "C" void kernel_launch(void* const* d_in, const int* in_sizes, int n_in,
                              void* d_out, int out_size, void* d_ws, size_t ws_size,
                              hipStream_t stream)
{
    const float* features = (const float*)d_in[0];
    const float* Wp   = (const float*)d_in[1];
    const float* bp   = (const float*)d_in[2];
    const float* Wqkv = (const float*)d_in[3];
    const float* bqkv = (const float*)d_in[4];
    const float* Wo   = (const float*)d_in[5];
    const float* bo   = (const float*)d_in[6];
    const float* W1   = (const float*)d_in[7];
    const float* b1   = (const float*)d_in[8];
    const float* W2   = (const float*)d_in[9];
    const float* b2   = (const float*)d_in[10];
    const float* g1   = (const float*)d_in[11];
    const float* be1  = (const float*)d_in[12];
    const float* g2   = (const float*)d_in[13];
    const float* be2  = (const float*)d_in[14];
    const float* Wout = (const float*)d_in[15];
    const float* bout = (const float*)d_in[16];
    float* out = (float*)d_out;

    char* ws = (char*)d_ws;
    bf16* X   = (bf16*)(ws);                    // 73728*256
    bf16* QKV = (bf16*)(ws + 37748736ull);      // 73728*768
    bf16* SAb = (bf16*)(ws + 150994944ull);     // 73728*256
    bf16* Xf  = (bf16*)(ws + 188743680ull);     // 73728*64
    bf16* WpB = (bf16*)(ws + 198180864ull);     // 256*64
    bf16* W2F = (bf16*)(ws + 198213632ull);     // 2 x 256*1024 fragments
    bf16* Wb  = (bf16*)(ws + 226492416ull);     // packed bf16 weights

    bf16* WqkvB = Wb;                  // 2 x 768*256
    bf16* WoB   = Wb + 393216;         // 2 x 256*256
    bf16* W1B   = Wb + 524288;         // 2 x 1024*256

    pack_all_k<<<6208, 256, 0, stream>>>(Wqkv, Wo, W1, W2, Wp,
                                         WqkvB, WoB, W1B, Wb + 1048576, WpB);
    pack_w2f_k<<<256, 256, 0, stream>>>(W2, W2F);

    feat_pack_k<<<dim3(144, 8), 256, 0, stream>>>(features, Xf);
    gemm_bt<false><<<dim3(2, 576), 256, 0, stream>>>(Xf, WpB, bp, X, 256, 64);

    for (int l = 0; l < 2; ++l) {
        gemm_bt<false><<<dim3(6, 576), 256, 0, stream>>>(
            X, WqkvB + l * 196608, bqkv + l * 768, QKV, 768, 256);
        attention_k<<<4608, 256, 0, stream>>>(QKV, SAb);
        gemm_ln_k<<<576, 256, 0, stream>>>(
            SAb, WoB + l * 65536, bo + l * 256, X,
            g1 + l * 256, be1 + l * 256, X, 256);
        ffn_fused_k<<<1152, 256, 0, stream>>>(
            X, W1B + l * 262144, b1 + l * 1024,
            W2F + l * 262144, b2 + l * 256,
            g2 + l * 256, be2 + l * 256, X);
    }

    out_proj_k<<<1152, 256, 0, stream>>>(X, Wout, bout, out);
}